// Round 1
// baseline (3383.863 us; speedup 1.0000x reference)
//
#include <hip/hip_runtime.h>
#include <cstdint>
#include <math.h>

#define TT  4
#define BB  16
#define CCH 512
#define HWD 1024
#define NHH 8
#define CWD (CCH / 32)   // 16 bit-words across channels

// ---------------------------------------------------------------------------
// Kernel 1: q/k 1x1-conv (fp64 accumulate) + BN + LIF, bitpack spikes to ws.
// Grid: (HW/64, C/64, B), 256 threads. Each thread: 4 o x 4 hw outputs, both
// branches. LIF membrane state lives in registers across the t-loop.
// ---------------------------------------------------------------------------
__global__ __launch_bounds__(256) void k_qk(
    const float* __restrict__ x,
    const float* __restrict__ qw, const float* __restrict__ qg, const float* __restrict__ qbe,
    const float* __restrict__ qm, const float* __restrict__ qva,
    const float* __restrict__ kw, const float* __restrict__ kg, const float* __restrict__ kbe,
    const float* __restrict__ km, const float* __restrict__ kva,
    uint32_t* __restrict__ qbits, uint32_t* __restrict__ kbits)
{
    __shared__ float Xs[64][68];
    __shared__ float Wqs[64][68];
    __shared__ float Wks[64][68];
    __shared__ uint32_t QB[2][64];
    __shared__ uint32_t KB[2][64];

    const int tid = threadIdx.x;
    const int to  = tid >> 4;     // 0..15 -> owns o = o0 + to*4 + j
    const int thw = tid & 15;     // 0..15 -> owns hw = hw0 + thw*4 + i
    const int b   = blockIdx.z;
    const int o0  = blockIdx.y * 64;
    const int hw0 = blockIdx.x * 64;

    double vq[4][4], vk[4][4];
#pragma unroll
    for (int j = 0; j < 4; ++j)
#pragma unroll
        for (int i = 0; i < 4; ++i) { vq[j][i] = 0.0; vk[j][i] = 0.0; }

    for (int t = 0; t < TT; ++t) {
        double aq[4][4], ak[4][4];
#pragma unroll
        for (int j = 0; j < 4; ++j)
#pragma unroll
            for (int i = 0; i < 4; ++i) { aq[j][i] = 0.0; ak[j][i] = 0.0; }

        for (int cb = 0; cb < 8; ++cb) {
            const int c0 = cb * 64;
#pragma unroll
            for (int r = 0; r < 4; ++r) {
                const int row = to * 4 + r;   // covers 0..63
                *(float4*)&Xs[row][thw * 4] =
                    *(const float4*)&x[(((size_t)t * BB + b) * CCH + c0 + row) * HWD + hw0 + thw * 4];
                *(float4*)&Wqs[row][thw * 4] =
                    *(const float4*)&qw[(size_t)(o0 + row) * CCH + c0 + thw * 4];
                *(float4*)&Wks[row][thw * 4] =
                    *(const float4*)&kw[(size_t)(o0 + row) * CCH + c0 + thw * 4];
            }
            __syncthreads();
#pragma unroll 4
            for (int cc = 0; cc < 64; ++cc) {
                const float4 xf = *(const float4*)&Xs[cc][thw * 4];
                const double x0 = (double)xf.x, x1 = (double)xf.y;
                const double x2 = (double)xf.z, x3 = (double)xf.w;
#pragma unroll
                for (int j = 0; j < 4; ++j) {
                    const double wq_ = (double)Wqs[to * 4 + j][cc];
                    const double wk_ = (double)Wks[to * 4 + j][cc];
                    aq[j][0] = fma(wq_, x0, aq[j][0]);
                    aq[j][1] = fma(wq_, x1, aq[j][1]);
                    aq[j][2] = fma(wq_, x2, aq[j][2]);
                    aq[j][3] = fma(wq_, x3, aq[j][3]);
                    ak[j][0] = fma(wk_, x0, ak[j][0]);
                    ak[j][1] = fma(wk_, x1, ak[j][1]);
                    ak[j][2] = fma(wk_, x2, ak[j][2]);
                    ak[j][3] = fma(wk_, x3, ak[j][3]);
                }
            }
            __syncthreads();
        }

        // zero the bit staging buffers
        if (tid < 128) { ((uint32_t*)QB)[tid] = 0u; ((uint32_t*)KB)[tid] = 0u; }
        __syncthreads();

        uint32_t qn[4] = {0u, 0u, 0u, 0u};
        uint32_t kn[4] = {0u, 0u, 0u, 0u};
#pragma unroll
        for (int j = 0; j < 4; ++j) {
            const int o = o0 + to * 4 + j;
            const double qi = (double)qg[o] / sqrt((double)qva[o] + 1e-5);
            const double qa = (double)qbe[o] - (double)qm[o] * qi;
            const double ki = (double)kg[o] / sqrt((double)kva[o] + 1e-5);
            const double ka = (double)kbe[o] - (double)km[o] * ki;
#pragma unroll
            for (int i = 0; i < 4; ++i) {
                double y = aq[j][i] * qi; y = y + qa;            // BN: y*inv + (beta-mean*inv)
                double v = vq[j][i];
                v = v + (y - v) * 0.5;                            // v += (x-v)/tau
                if (v >= 1.0) { qn[i] |= (1u << j); v = 0.0; }    // spike + hard reset
                vq[j][i] = v;

                y = ak[j][i] * ki; y = y + ka;
                v = vk[j][i];
                v = v + (y - v) * 0.5;
                if (v >= 1.0) { kn[i] |= (1u << j); v = 0.0; }
                vk[j][i] = v;
            }
        }
        const int wsel = to >> 3;
        const int sh   = (to & 7) * 4;
#pragma unroll
        for (int i = 0; i < 4; ++i) {
            if (qn[i]) atomicOr(&QB[wsel][thw * 4 + i], qn[i] << sh);
            if (kn[i]) atomicOr(&KB[wsel][thw * 4 + i], kn[i] << sh);
        }
        __syncthreads();
        if (tid < 128) {
            const int ws = tid >> 6, hl = tid & 63;
            const size_t base = (((size_t)t * BB + b) * CWD + (o0 >> 5) + ws) * HWD + hw0 + hl;
            qbits[base] = QB[ws][hl];
            kbits[base] = KB[ws][hl];
        }
        __syncthreads();
    }
}

// ---------------------------------------------------------------------------
// Kernel 2: head-sum of q spikes (popcount of 64 bits) + LIF at 0.5 -> attn.
// All arithmetic is exactly-representable dyadic fp64 -> bitwise exact.
// ---------------------------------------------------------------------------
__global__ __launch_bounds__(256) void k_attn(
    const uint32_t* __restrict__ qbits, uint8_t* __restrict__ attn)
{
    const int idx = blockIdx.x * 256 + threadIdx.x;   // b*NH*HW total
    const int hw = idx & (HWD - 1);
    const int h  = (idx >> 10) & (NHH - 1);
    const int b  = idx >> 13;
    double v = 0.0;
#pragma unroll
    for (int t = 0; t < TT; ++t) {
        const uint32_t w0 = qbits[(((size_t)t * BB + b) * CWD + h * 2    ) * HWD + hw];
        const uint32_t w1 = qbits[(((size_t)t * BB + b) * CWD + h * 2 + 1) * HWD + hw];
        const double q = (double)(__popc(w0) + __popc(w1));
        v = v + (q - v) * 0.5;
        const uint8_t s = (v >= 0.5) ? (uint8_t)1 : (uint8_t)0;
        attn[(((size_t)t * BB + b) * NHH + h) * HWD + hw] = s;
        if (s) v = 0.0;
    }
}

// ---------------------------------------------------------------------------
// Kernel 3: proj conv over binary y = attn & k (masked fp64 adds) + bias + BN
// + LIF -> final spikes (float 0/1) to d_out.
// ---------------------------------------------------------------------------
__global__ __launch_bounds__(256) void k_proj(
    const float* __restrict__ pw, const float* __restrict__ pb,
    const float* __restrict__ pg, const float* __restrict__ pbe,
    const float* __restrict__ pm, const float* __restrict__ pva,
    const uint32_t* __restrict__ kbits, const uint8_t* __restrict__ attn,
    float* __restrict__ out)
{
    __shared__ float Wps[64][68];
    __shared__ uint32_t KWs[2][64];
    __shared__ uint8_t ATs[64];

    const int tid = threadIdx.x;
    const int to  = tid >> 4;
    const int thw = tid & 15;
    const int b   = blockIdx.z;
    const int o0  = blockIdx.y * 64;
    const int hw0 = blockIdx.x * 64;

    double vv[4][4];
#pragma unroll
    for (int j = 0; j < 4; ++j)
#pragma unroll
        for (int i = 0; i < 4; ++i) vv[j][i] = 0.0;

    for (int t = 0; t < TT; ++t) {
        double acc[4][4];
#pragma unroll
        for (int j = 0; j < 4; ++j)
#pragma unroll
            for (int i = 0; i < 4; ++i) acc[j][i] = 0.0;

        for (int cb = 0; cb < 8; ++cb) {   // c-block == head cb (64 channels)
            const int c0 = cb * 64;
#pragma unroll
            for (int r = 0; r < 4; ++r) {
                const int row = to * 4 + r;
                *(float4*)&Wps[row][thw * 4] =
                    *(const float4*)&pw[(size_t)(o0 + row) * CCH + c0 + thw * 4];
            }
            if (tid < 128) {
                const int ws = tid >> 6, hl = tid & 63;
                KWs[ws][hl] = kbits[(((size_t)t * BB + b) * CWD + cb * 2 + ws) * HWD + hw0 + hl];
            }
            if (tid < 64)
                ATs[tid] = attn[(((size_t)t * BB + b) * NHH + cb) * HWD + hw0 + tid];
            __syncthreads();

            uint32_t m0[4], m1[4];
#pragma unroll
            for (int i = 0; i < 4; ++i) {
                const int hl = thw * 4 + i;
                const uint32_t a = ATs[hl] ? 0xFFFFFFFFu : 0u;
                m0[i] = KWs[0][hl] & a;
                m1[i] = KWs[1][hl] & a;
            }
#pragma unroll 4
            for (int cc = 0; cc < 32; ++cc) {
#pragma unroll
                for (int j = 0; j < 4; ++j) {
                    const double w = (double)Wps[to * 4 + j][cc];
#pragma unroll
                    for (int i = 0; i < 4; ++i)
                        acc[j][i] += ((m0[i] >> cc) & 1u) ? w : 0.0;
                }
            }
#pragma unroll 4
            for (int cc = 0; cc < 32; ++cc) {
#pragma unroll
                for (int j = 0; j < 4; ++j) {
                    const double w = (double)Wps[to * 4 + j][cc + 32];
#pragma unroll
                    for (int i = 0; i < 4; ++i)
                        acc[j][i] += ((m1[i] >> cc) & 1u) ? w : 0.0;
                }
            }
            __syncthreads();
        }

#pragma unroll
        for (int j = 0; j < 4; ++j) {
            const int o = o0 + to * 4 + j;
            const double bias = (double)pb[o];
            const double inv  = (double)pg[o] / sqrt((double)pva[o] + 1e-5);
            const double add  = (double)pbe[o] - (double)pm[o] * inv;
            float4 res;
            float* rp = (float*)&res;
#pragma unroll
            for (int i = 0; i < 4; ++i) {
                double y = acc[j][i] + bias;   // conv bias first (matches ref order)
                y = y * inv; y = y + add;      // then BN affine
                double v = vv[j][i];
                v = v + (y - v) * 0.5;
                if (v >= 1.0) { rp[i] = 1.0f; v = 0.0; }
                else          { rp[i] = 0.0f; }
                vv[j][i] = v;
            }
            *(float4*)&out[(((size_t)t * BB + b) * CCH + o) * HWD + hw0 + thw * 4] = res;
        }
    }
}

extern "C" void kernel_launch(void* const* d_in, const int* in_sizes, int n_in,
                              void* d_out, int out_size, void* d_ws, size_t ws_size,
                              hipStream_t stream)
{
    (void)in_sizes; (void)n_in; (void)out_size; (void)ws_size;

    const float* x   = (const float*)d_in[0];
    const float* qw  = (const float*)d_in[1];
    const float* qg  = (const float*)d_in[2];
    const float* qbe = (const float*)d_in[3];
    const float* qm  = (const float*)d_in[4];
    const float* qv  = (const float*)d_in[5];
    const float* kw  = (const float*)d_in[6];
    const float* kg  = (const float*)d_in[7];
    const float* kbe = (const float*)d_in[8];
    const float* km  = (const float*)d_in[9];
    const float* kv  = (const float*)d_in[10];
    const float* pw  = (const float*)d_in[11];
    const float* pb  = (const float*)d_in[12];
    const float* pg  = (const float*)d_in[13];
    const float* pbe = (const float*)d_in[14];
    const float* pm  = (const float*)d_in[15];
    const float* pv  = (const float*)d_in[16];

    uint32_t* qbits = (uint32_t*)d_ws;                       // 4 MiB
    uint32_t* kbits = qbits + (size_t)TT * BB * CWD * HWD;   // 4 MiB
    uint8_t*  attn  = (uint8_t*)(kbits + (size_t)TT * BB * CWD * HWD); // 512 KiB
    float* out = (float*)d_out;

    dim3 grid(HWD / 64, CCH / 64, BB);   // (16, 8, 16)
    dim3 blk(256);

    k_qk<<<grid, blk, 0, stream>>>(x, qw, qg, qbe, qm, qv,
                                   kw, kg, kbe, km, kv, qbits, kbits);
    k_attn<<<dim3((BB * NHH * HWD) / 256), blk, 0, stream>>>(qbits, attn);
    k_proj<<<grid, blk, 0, stream>>>(pw, pb, pg, pbe, pm, pv, kbits, attn, out);
}

// Round 3
// 1969.916 us; speedup vs baseline: 1.7178x; 1.7178x over previous
//
#include <hip/hip_runtime.h>
#include <cstdint>
#include <math.h>

#define TT 4
#define BB 16
#define CCH 512
#define HWD 1024
#define NHH 8
#define CWD 16   // 512/32 bit-words across channels

typedef __attribute__((ext_vector_type(4))) double f64x4;

// ---------------------------------------------------------------------------
// Layout probe for v_mfma_f64_16x16x4_f64. Two MFMAs with known inputs give
// exact integer outputs that (a) identify the A/B lane->(i,k) mapping form and
// (b) directly measure the D (row,col) of every (reg,lane). fp64-exact.
//   probeA = mfma(a=lane, b=1, c=0):  D[i][j] = sum_k A[i][k]
//     form1 (i=l&15,k=l>>4): A[i][k]=i+16k -> 4i+96   (mod 16 in {0,4,8,12})
//     form2 (i=l>>2,k=l&3):  A[i][k]=4i+k  -> 16i+6   (mod 16 == 6)
//   probeB symmetric for columns.
// ---------------------------------------------------------------------------
__device__ __forceinline__ void probe_layout(int lane, int rowD[4], int colD[4],
                                             int& aRow, int& aK, int& bCol, int& bK)
{
    const f64x4 z = {0.0, 0.0, 0.0, 0.0};
    f64x4 pa = __builtin_amdgcn_mfma_f64_16x16x4f64((double)lane, 1.0, z, 0, 0, 0);
    f64x4 pb = __builtin_amdgcn_mfma_f64_16x16x4f64(1.0, (double)lane, z, 0, 0, 0);
    bool A2 = false, B2 = false;
#pragma unroll
    for (int r = 0; r < 4; ++r) {
        const int va = (int)pa[r];
        if ((va & 15) == 6) { rowD[r] = (va - 6) >> 4; A2 = true; }
        else                { rowD[r] = (va - 96) >> 2; }
        const int vb = (int)pb[r];
        if ((vb & 15) == 6) { colD[r] = (vb - 6) >> 4; B2 = true; }
        else                { colD[r] = (vb - 96) >> 2; }
    }
    aRow = A2 ? (lane >> 2) : (lane & 15);
    aK   = A2 ? (lane & 3)  : (lane >> 4);
    bCol = B2 ? (lane >> 2) : (lane & 15);
    bK   = B2 ? (lane & 3)  : (lane >> 4);
}

// ---------------------------------------------------------------------------
// Kernel 1: q/k 1x1-conv via fp64 MFMA + BN + LIF, bitpack spikes to ws.
// Block = 32o x 32hw, 4 waves (2x2 of 16x16 tiles), all 4 t accumulated
// simultaneously; LIF runs in registers at the end.
// ---------------------------------------------------------------------------
__global__ __launch_bounds__(256) void k_qk(
    const float* __restrict__ x,
    const float* __restrict__ qw, const float* __restrict__ qg, const float* __restrict__ qbe,
    const float* __restrict__ qm, const float* __restrict__ qva,
    const float* __restrict__ kw, const float* __restrict__ kg, const float* __restrict__ kbe,
    const float* __restrict__ km, const float* __restrict__ kva,
    uint32_t* __restrict__ qbits, uint32_t* __restrict__ kbits)
{
    __shared__ float Xs[TT][64][32];   // physical col = hw ^ ((c&1)<<4)
    __shared__ float Wqs[32][65];
    __shared__ float Wks[32][65];
    __shared__ uint32_t QB[2][TT][32];

    const int tid  = threadIdx.x;
    const int lane = tid & 63;
    const int wid  = tid >> 6;
    const int b    = blockIdx.z;
    const int o0   = blockIdx.y * 32;
    const int hw0  = blockIdx.x * 32;
    const int wo   = (wid >> 1) * 16;   // wave o offset in block
    const int whw  = (wid & 1) * 16;    // wave hw offset in block

    int rowD[4], colD[4], aRow, aK, bCol, bK;
    probe_layout(lane, rowD, colD, aRow, aK, bCol, bK);
    const int xcol = (whw + bCol) ^ ((bK & 1) << 4);   // (kk*4+bK)&1 == bK&1

    f64x4 accq[TT], acck[TT];
#pragma unroll
    for (int t = 0; t < TT; ++t) {
        accq[t] = (f64x4){0.0, 0.0, 0.0, 0.0};
        acck[t] = (f64x4){0.0, 0.0, 0.0, 0.0};
    }

    const int sc  = tid >> 3;          // 0..31: c row for X staging
    const int shw = (tid & 7) * 4;     // hw4 for X staging
    const int swo = tid >> 4;          // 0..15: o row for W staging
    const int swc = (tid & 15) * 4;    // c4 for W staging

    for (int cb = 0; cb < 8; ++cb) {
        const int c0 = cb * 64;
        __syncthreads();
#pragma unroll
        for (int t = 0; t < TT; ++t) {
#pragma unroll
            for (int it = 0; it < 2; ++it) {
                const int c = sc + it * 32;
                const float4 v = *(const float4*)&x[(((size_t)t * BB + b) * CCH + c0 + c) * HWD + hw0 + shw];
                *(float4*)&Xs[t][c][shw ^ ((c & 1) << 4)] = v;
            }
        }
#pragma unroll
        for (int it = 0; it < 2; ++it) {
            const int o = swo + it * 16;
            *(float4*)&Wqs[o][swc] = *(const float4*)&qw[(size_t)(o0 + o) * CCH + c0 + swc];
            *(float4*)&Wks[o][swc] = *(const float4*)&kw[(size_t)(o0 + o) * CCH + c0 + swc];
        }
        __syncthreads();

        double aq[16], ak[16];
#pragma unroll
        for (int kk = 0; kk < 16; ++kk) {
            aq[kk] = (double)Wqs[wo + aRow][kk * 4 + aK];
            ak[kk] = (double)Wks[wo + aRow][kk * 4 + aK];
        }
#pragma unroll
        for (int kk = 0; kk < 16; ++kk) {
            const int c = kk * 4 + bK;
            const double b0 = (double)Xs[0][c][xcol];
            const double b1 = (double)Xs[1][c][xcol];
            const double b2 = (double)Xs[2][c][xcol];
            const double b3 = (double)Xs[3][c][xcol];
            accq[0] = __builtin_amdgcn_mfma_f64_16x16x4f64(aq[kk], b0, accq[0], 0, 0, 0);
            acck[0] = __builtin_amdgcn_mfma_f64_16x16x4f64(ak[kk], b0, acck[0], 0, 0, 0);
            accq[1] = __builtin_amdgcn_mfma_f64_16x16x4f64(aq[kk], b1, accq[1], 0, 0, 0);
            acck[1] = __builtin_amdgcn_mfma_f64_16x16x4f64(ak[kk], b1, acck[1], 0, 0, 0);
            accq[2] = __builtin_amdgcn_mfma_f64_16x16x4f64(aq[kk], b2, accq[2], 0, 0, 0);
            acck[2] = __builtin_amdgcn_mfma_f64_16x16x4f64(ak[kk], b2, acck[2], 0, 0, 0);
            accq[3] = __builtin_amdgcn_mfma_f64_16x16x4f64(aq[kk], b3, accq[3], 0, 0, 0);
            acck[3] = __builtin_amdgcn_mfma_f64_16x16x4f64(ak[kk], b3, acck[3], 0, 0, 0);
        }
    }

    // ---- BN + LIF + bitpack ----
    ((uint32_t*)QB)[tid] = 0u;     // 2*4*32 = 256 words
    __syncthreads();

    double qi[4], qa[4], ki[4], ka[4];
#pragma unroll
    for (int r = 0; r < 4; ++r) {
        const int o = o0 + wo + rowD[r];
        const double qiv = (double)qg[o] / sqrt((double)qva[o] + 1e-5);
        qi[r] = qiv; qa[r] = (double)qbe[o] - (double)qm[o] * qiv;
        const double kiv = (double)kg[o] / sqrt((double)kva[o] + 1e-5);
        ki[r] = kiv; ka[r] = (double)kbe[o] - (double)km[o] * kiv;
    }
    double vq[4] = {0.0, 0.0, 0.0, 0.0}, vk[4] = {0.0, 0.0, 0.0, 0.0};
#pragma unroll
    for (int t = 0; t < TT; ++t) {
#pragma unroll
        for (int r = 0; r < 4; ++r) {
            const uint32_t bit = 1u << (wo + rowD[r]);
            double y = accq[t][r] * qi[r]; y = y + qa[r];
            double v = vq[r];
            v = v + (y - v) * 0.5;
            if (v >= 1.0) { atomicOr(&QB[0][t][whw + colD[r]], bit); v = 0.0; }
            vq[r] = v;
            y = acck[t][r] * ki[r]; y = y + ka[r];
            v = vk[r];
            v = v + (y - v) * 0.5;
            if (v >= 1.0) { atomicOr(&QB[1][t][whw + colD[r]], bit); v = 0.0; }
            vk[r] = v;
        }
    }
    __syncthreads();
    {
        const int br = tid >> 7, t = (tid >> 5) & 3, hw = tid & 31;
        const uint32_t w = QB[br][t][hw];
        uint32_t* dst = br ? kbits : qbits;
        dst[(((size_t)t * BB + b) * CWD + blockIdx.y) * HWD + hw0 + hw] = w;
    }
}

// ---------------------------------------------------------------------------
// Kernel 2: head-sum of q spikes (popcount) + LIF at 0.5 -> attn (exact dyadic)
// ---------------------------------------------------------------------------
__global__ __launch_bounds__(256) void k_attn(
    const uint32_t* __restrict__ qbits, uint8_t* __restrict__ attn)
{
    const int idx = blockIdx.x * 256 + threadIdx.x;
    const int hw = idx & (HWD - 1);
    const int h  = (idx >> 10) & (NHH - 1);
    const int b  = idx >> 13;
    double v = 0.0;
#pragma unroll
    for (int t = 0; t < TT; ++t) {
        const uint32_t w0 = qbits[(((size_t)t * BB + b) * CWD + h * 2    ) * HWD + hw];
        const uint32_t w1 = qbits[(((size_t)t * BB + b) * CWD + h * 2 + 1) * HWD + hw];
        const double q = (double)(__popc(w0) + __popc(w1));
        v = v + (q - v) * 0.5;
        const uint8_t s = (v >= 0.5) ? (uint8_t)1 : (uint8_t)0;
        attn[(((size_t)t * BB + b) * NHH + h) * HWD + hw] = s;
        if (s) v = 0.0;
    }
}

// ---------------------------------------------------------------------------
// Kernel 3: proj conv via fp64 MFMA over binary y = attn & k, + bias + BN +
// LIF -> final spikes (float 0/1).
// ---------------------------------------------------------------------------
__global__ __launch_bounds__(256) void k_proj(
    const float* __restrict__ pw, const float* __restrict__ pb,
    const float* __restrict__ pg, const float* __restrict__ pbe,
    const float* __restrict__ pm, const float* __restrict__ pva,
    const uint32_t* __restrict__ kbits, const uint8_t* __restrict__ attn,
    float* __restrict__ out)
{
    __shared__ float Ys[TT][64][32];   // physical col = hw ^ ((c&1)<<4)
    __shared__ float Wps[32][65];
    __shared__ uint32_t MW[TT][2][32];

    const int tid  = threadIdx.x;
    const int lane = tid & 63;
    const int wid  = tid >> 6;
    const int b    = blockIdx.z;
    const int o0   = blockIdx.y * 32;
    const int hw0  = blockIdx.x * 32;
    const int wo   = (wid >> 1) * 16;
    const int whw  = (wid & 1) * 16;

    int rowD[4], colD[4], aRow, aK, bCol, bK;
    probe_layout(lane, rowD, colD, aRow, aK, bCol, bK);
    const int ycol = (whw + bCol) ^ ((bK & 1) << 4);

    f64x4 acc[TT];
#pragma unroll
    for (int t = 0; t < TT; ++t) acc[t] = (f64x4){0.0, 0.0, 0.0, 0.0};

    const int swo = tid >> 4;
    const int swc = (tid & 15) * 4;

    for (int cb = 0; cb < 8; ++cb) {
        const int c0 = cb * 64;
        __syncthreads();
#pragma unroll
        for (int it = 0; it < 2; ++it) {
            const int o = swo + it * 16;
            *(float4*)&Wps[o][swc] = *(const float4*)&pw[(size_t)(o0 + o) * CCH + c0 + swc];
        }
        {   // stage attn-masked k bit-words
            const int t = tid >> 6, j = (tid >> 5) & 1, hw = tid & 31;
            const uint32_t w = kbits[(((size_t)t * BB + b) * CWD + cb * 2 + j) * HWD + hw0 + hw];
            const uint32_t a = attn[(((size_t)t * BB + b) * NHH + cb) * HWD + hw0 + hw] ? 0xFFFFFFFFu : 0u;
            MW[t][j][hw] = w & a;
        }
        __syncthreads();
        {   // expand bits to f32 0/1 tile
            const int hw = tid & 31, t = (tid >> 5) & 3, half = tid >> 7;
            const uint32_t w = MW[t][half][hw];
#pragma unroll
            for (int cl = 0; cl < 32; ++cl) {
                const int c = half * 32 + cl;
                Ys[t][c][hw ^ ((c & 1) << 4)] = ((w >> cl) & 1u) ? 1.0f : 0.0f;
            }
        }
        double ap[16];
#pragma unroll
        for (int kk = 0; kk < 16; ++kk)
            ap[kk] = (double)Wps[wo + aRow][kk * 4 + aK];
        __syncthreads();

#pragma unroll
        for (int kk = 0; kk < 16; ++kk) {
            const int c = kk * 4 + bK;
            const double b0 = (double)Ys[0][c][ycol];
            const double b1 = (double)Ys[1][c][ycol];
            const double b2 = (double)Ys[2][c][ycol];
            const double b3 = (double)Ys[3][c][ycol];
            acc[0] = __builtin_amdgcn_mfma_f64_16x16x4f64(ap[kk], b0, acc[0], 0, 0, 0);
            acc[1] = __builtin_amdgcn_mfma_f64_16x16x4f64(ap[kk], b1, acc[1], 0, 0, 0);
            acc[2] = __builtin_amdgcn_mfma_f64_16x16x4f64(ap[kk], b2, acc[2], 0, 0, 0);
            acc[3] = __builtin_amdgcn_mfma_f64_16x16x4f64(ap[kk], b3, acc[3], 0, 0, 0);
        }
    }

    // ---- bias + BN + LIF + store ----
    double pi[4], pa[4], pbv[4];
#pragma unroll
    for (int r = 0; r < 4; ++r) {
        const int o = o0 + wo + rowD[r];
        const double inv = (double)pg[o] / sqrt((double)pva[o] + 1e-5);
        pi[r] = inv;
        pa[r] = (double)pbe[o] - (double)pm[o] * inv;
        pbv[r] = (double)pb[o];
    }
    double vv[4] = {0.0, 0.0, 0.0, 0.0};
#pragma unroll
    for (int t = 0; t < TT; ++t) {
#pragma unroll
        for (int r = 0; r < 4; ++r) {
            double y = acc[t][r] + pbv[r];   // conv bias first
            y = y * pi[r]; y = y + pa[r];    // BN affine
            double v = vv[r];
            v = v + (y - v) * 0.5;
            float s;
            if (v >= 1.0) { s = 1.0f; v = 0.0; } else { s = 0.0f; }
            vv[r] = v;
            out[(((size_t)t * BB + b) * CCH + o0 + wo + rowD[r]) * HWD + hw0 + whw + colD[r]] = s;
        }
    }
}

extern "C" void kernel_launch(void* const* d_in, const int* in_sizes, int n_in,
                              void* d_out, int out_size, void* d_ws, size_t ws_size,
                              hipStream_t stream)
{
    (void)in_sizes; (void)n_in; (void)out_size; (void)ws_size;

    const float* x   = (const float*)d_in[0];
    const float* qw  = (const float*)d_in[1];
    const float* qg  = (const float*)d_in[2];
    const float* qbe = (const float*)d_in[3];
    const float* qm  = (const float*)d_in[4];
    const float* qv  = (const float*)d_in[5];
    const float* kw  = (const float*)d_in[6];
    const float* kg  = (const float*)d_in[7];
    const float* kbe = (const float*)d_in[8];
    const float* km  = (const float*)d_in[9];
    const float* kv  = (const float*)d_in[10];
    const float* pw  = (const float*)d_in[11];
    const float* pb  = (const float*)d_in[12];
    const float* pg  = (const float*)d_in[13];
    const float* pbe = (const float*)d_in[14];
    const float* pm  = (const float*)d_in[15];
    const float* pv  = (const float*)d_in[16];

    uint32_t* qbits = (uint32_t*)d_ws;                                  // 4 MiB
    uint32_t* kbits = qbits + (size_t)TT * BB * CWD * HWD;              // 4 MiB
    uint8_t*  attn  = (uint8_t*)(kbits + (size_t)TT * BB * CWD * HWD);  // 512 KiB
    float* out = (float*)d_out;

    dim3 grid(HWD / 32, CCH / 32, BB);   // (32, 16, 16)
    dim3 blk(256);

    k_qk<<<grid, blk, 0, stream>>>(x, qw, qg, qbe, qm, qv,
                                   kw, kg, kbe, km, kv, qbits, kbits);
    k_attn<<<dim3((BB * NHH * HWD) / 256), blk, 0, stream>>>(qbits, attn);
    k_proj<<<grid, blk, 0, stream>>>(pw, pb, pg, pbe, pm, pv, kbits, attn, out);
}

// Round 6
// 813.054 us; speedup vs baseline: 4.1619x; 2.4229x over previous
//
#include <hip/hip_runtime.h>
#include <cstdint>
#include <math.h>

#define TT 4
#define BB 16
#define CCH 512
#define HWD 1024
#define NHH 8
#define NW 16            // 512/32 channel bit-words
#define MQK 1.5e-4       // flag margin q/k (error std ~1.5e-5 -> 10 sigma)
#define MPROJ 1.0e-4     // flag margin proj
#define CAPQ 49152
#define CAPP 16384

typedef __attribute__((ext_vector_type(4))) float f32x4;
typedef __attribute__((ext_vector_type(8))) short s16x8;
typedef __attribute__((ext_vector_type(4))) uint32_t u32x4;

static __device__ __forceinline__ f32x4 MFMA(s16x8 a, s16x8 b, f32x4 c) {
    return __builtin_amdgcn_mfma_f32_16x16x32_bf16(a, b, c, 0, 0, 0);
}

// pack the two high halves (bf16 truncations) of u0,u1 into one u32
static __device__ __forceinline__ uint32_t hi_pair(uint32_t u0, uint32_t u1) {
#if __has_builtin(__builtin_amdgcn_perm)
    return __builtin_amdgcn_perm(u1, u0, 0x07060302u);
#else
    return (u1 & 0xFFFF0000u) | (u0 >> 16);
#endif
}

struct SplitPair { uint32_t h, l; };

// truncation split: x = bf(h) + bf(l) + r, |r| <= 2^-15 |x|; ~6 VALU per pair
static __device__ __forceinline__ SplitPair split_pair(float f0, float f1) {
    const uint32_t u0 = __builtin_bit_cast(uint32_t, f0);
    const uint32_t u1 = __builtin_bit_cast(uint32_t, f1);
    SplitPair r;
    r.h = hi_pair(u0, u1);
    const float r0 = f0 - __builtin_bit_cast(float, u0 & 0xFFFF0000u);
    const float r1 = f1 - __builtin_bit_cast(float, u1 & 0xFFFF0000u);
    r.l = hi_pair(__builtin_bit_cast(uint32_t, r0), __builtin_bit_cast(uint32_t, r1));
    return r;
}

static __device__ __forceinline__ void split_frag8(const float f[8], s16x8& h, s16x8& l) {
    u32x4 hw_, lw_;
    const SplitPair p0 = split_pair(f[0], f[1]);
    const SplitPair p1 = split_pair(f[2], f[3]);
    const SplitPair p2 = split_pair(f[4], f[5]);
    const SplitPair p3 = split_pair(f[6], f[7]);
    hw_[0] = p0.h; lw_[0] = p0.l;
    hw_[1] = p1.h; lw_[1] = p1.l;
    hw_[2] = p2.h; lw_[2] = p2.l;
    hw_[3] = p3.h; lw_[3] = p3.l;
    h = __builtin_bit_cast(s16x8, hw_);
    l = __builtin_bit_cast(s16x8, lw_);
}

static __device__ __forceinline__ void load_split_frag(const float* p, s16x8& h, s16x8& l) {
    const float4 a = *(const float4*)p;
    const float4 b4 = *(const float4*)(p + 4);
    const float f[8] = {a.x, a.y, a.z, a.w, b4.x, b4.y, b4.z, b4.w};
    split_frag8(f, h, l);
}

// ---------------------------------------------------------------------------
// Layout self-probe for mfma_f32_16x16x32_bf16 (integers exact in bf16/f32):
//   pa = mfma(a=lane, b=1): D[i][j] = sum_k A[i][k]
//     form1 (row=l&15, k=(l>>4)*8+e): 32*i + 768   ((v-48)%128 != 0)
//     form2 (row=l>>2, k=(l&3)*8+e): 128*i + 48    ((v-48)%128 == 0)
//   pb symmetric for B/cols. Gives A/B form + exact D (row,col) per reg.
// ---------------------------------------------------------------------------
static __device__ __forceinline__ void probe_bf16(int lane, int rowD[4], int colD[4],
                                                  int& aRow, int& aKb, int& bCol, int& bKb)
{
    const f32x4 z = {0.f, 0.f, 0.f, 0.f};
    const short lv = (short)(__builtin_bit_cast(uint32_t, (float)lane) >> 16);
    const short one = (short)0x3F80;
    const s16x8 av = {lv, lv, lv, lv, lv, lv, lv, lv};
    const s16x8 ov = {one, one, one, one, one, one, one, one};
    const f32x4 pa = MFMA(av, ov, z);
    const f32x4 pb = MFMA(ov, av, z);
    bool A2 = false, B2 = false;
#pragma unroll
    for (int r = 0; r < 4; ++r) {
        const int va = (int)pa[r];
        if (((va - 48) & 127) == 0) { rowD[r] = (va - 48) >> 7; A2 = true; }
        else                        { rowD[r] = (va - 768) >> 5; }
        const int vb = (int)pb[r];
        if (((vb - 48) & 127) == 0) { colD[r] = (vb - 48) >> 7; B2 = true; }
        else                        { colD[r] = (vb - 768) >> 5; }
    }
    aRow = A2 ? (lane >> 2) : (lane & 15);
    aKb  = A2 ? (lane & 3) * 8 : (lane >> 4) * 8;
    bCol = B2 ? (lane >> 2) : (lane & 15);
    bKb  = B2 ? (lane & 3) * 8 : (lane >> 4) * 8;
}

__global__ void k_zero(unsigned int* ctr) {
    if (threadIdx.x < 2) ctr[threadIdx.x] = 0u;
}

// ---------------------------------------------------------------------------
// Kernel 1: q/k conv1x1 via bf16-split MFMA (3 cross terms) + fp64 BN/LIF,
// spikes bitpacked, near-threshold chains flagged. Block = 64o x 32hw,
// 4 waves (2o x 2hw), wave = 32o x 16hw, both branches. No LDS in main loop.
// ---------------------------------------------------------------------------
__global__ __launch_bounds__(256) void k_qk(
    const float* __restrict__ x,
    const float* __restrict__ qw, const float* __restrict__ qg, const float* __restrict__ qbe,
    const float* __restrict__ qm, const float* __restrict__ qva,
    const float* __restrict__ kw, const float* __restrict__ kg, const float* __restrict__ kbe,
    const float* __restrict__ km, const float* __restrict__ kva,
    uint32_t* __restrict__ qbits, uint32_t* __restrict__ kbits,
    unsigned int* __restrict__ ctr, uint32_t* __restrict__ list)
{
    __shared__ uint32_t QB[2][2][TT][32];   // [branch][o-word][t][hw]

    const int tid = threadIdx.x, lane = tid & 63, wid = tid >> 6;
    const int b   = blockIdx.z;
    const int o0  = blockIdx.y * 64, hw0 = blockIdx.x * 32;
    const int worow = (wid >> 1) * 32, whw = (wid & 1) * 16;

    int rowD[4], colD[4], aRow, aKb, bCol, bKb;
    probe_bf16(lane, rowD, colD, aRow, aKb, bCol, bKb);
    const int hwB = hw0 + whw + bCol;

    f32x4 aq[TT][2], ak[TT][2];
#pragma unroll
    for (int t = 0; t < TT; ++t)
#pragma unroll
        for (int ot = 0; ot < 2; ++ot) {
            aq[t][ot] = (f32x4){0.f, 0.f, 0.f, 0.f};
            ak[t][ot] = (f32x4){0.f, 0.f, 0.f, 0.f};
        }

#pragma unroll 1
    for (int ks = 0; ks < 16; ++ks) {
        const int c0 = ks * 32;
        s16x8 Aqh[2], Aql[2], Akh[2], Akl[2];
#pragma unroll
        for (int ot = 0; ot < 2; ++ot) {
            const size_t ro = (size_t)(o0 + worow + ot * 16 + aRow) * CCH + c0 + aKb;
            load_split_frag(qw + ro, Aqh[ot], Aql[ot]);
            load_split_frag(kw + ro, Akh[ot], Akl[ot]);
        }
#pragma unroll
        for (int t = 0; t < TT; ++t) {
            const float* xp = x + ((size_t)(t * BB + b) * CCH + c0 + bKb) * HWD + hwB;
            float f[8];
#pragma unroll
            for (int e = 0; e < 8; ++e) f[e] = xp[(size_t)e * HWD];
            s16x8 Bh, Bl;
            split_frag8(f, Bh, Bl);
#pragma unroll
            for (int ot = 0; ot < 2; ++ot) {
                aq[t][ot] = MFMA(Aqh[ot], Bh, aq[t][ot]);
                aq[t][ot] = MFMA(Aqh[ot], Bl, aq[t][ot]);
                aq[t][ot] = MFMA(Aql[ot], Bh, aq[t][ot]);
                ak[t][ot] = MFMA(Akh[ot], Bh, ak[t][ot]);
                ak[t][ot] = MFMA(Akh[ot], Bl, ak[t][ot]);
                ak[t][ot] = MFMA(Akl[ot], Bh, ak[t][ot]);
            }
        }
    }

    // ---- epilogue: fp64 BN + LIF, flags, bitpack ----
    ((uint32_t*)QB)[tid] = 0u;
    ((uint32_t*)QB)[tid + 256] = 0u;
    __syncthreads();

    auto chains = [&](f32x4 (&acc)[TT][2], const float* g, const float* be,
                      const float* mn, const float* va, int br) {
#pragma unroll
        for (int ot = 0; ot < 2; ++ot)
#pragma unroll
            for (int r = 0; r < 4; ++r) {
                const int orow = worow + ot * 16 + rowD[r];    // 0..63
                const int o = o0 + orow;
                const double inv = (double)g[o] / sqrt((double)va[o] + 1e-5);
                const double add = (double)be[o] - (double)mn[o] * inv;
                const uint32_t bit = 1u << (orow & 31);
                const int ow = orow >> 5;
                const int hwq = whw + colD[r];
                double v = 0.0; bool fl = false;
#pragma unroll
                for (int t = 0; t < TT; ++t) {
                    const double y = (double)acc[t][ot][r] * inv + add;
                    v = v + (y - v) * 0.5;
                    if (fabs(v - 1.0) < MQK) fl = true;
                    if (v >= 1.0) { atomicOr(&QB[br][ow][t][hwq], bit); v = 0.0; }
                }
                if (fl) {
                    const unsigned int idx = atomicAdd(ctr, 1u);
                    if (idx < CAPQ)
                        list[idx] = (uint32_t)((br << 23) | (o << 14) | (b << 10) | (hw0 + hwq));
                }
            }
    };
    chains(aq, qg, qbe, qm, qva, 0);
    chains(ak, kg, kbe, km, kva, 1);
    __syncthreads();

#pragma unroll
    for (int u = 0; u < 2; ++u) {
        const int idx = tid + u * 256;   // 0..511
        const int br = idx >> 8, ow = (idx >> 7) & 1, t = (idx >> 5) & 3, hwq = idx & 31;
        uint32_t* dst = br ? kbits : qbits;
        dst[((size_t)(t * BB + b) * NW + (o0 >> 5) + ow) * HWD + hw0 + hwq] = QB[br][ow][t][hwq];
    }
}

// ---------------------------------------------------------------------------
// Kernel 2: exact fp64 recompute of flagged q/k chains; patch spike bits.
// ---------------------------------------------------------------------------
__global__ __launch_bounds__(256) void k_fix_qk(
    const float* __restrict__ x,
    const float* __restrict__ qw, const float* __restrict__ qg, const float* __restrict__ qbe,
    const float* __restrict__ qm, const float* __restrict__ qva,
    const float* __restrict__ kw, const float* __restrict__ kg, const float* __restrict__ kbe,
    const float* __restrict__ km, const float* __restrict__ kva,
    const unsigned int* __restrict__ ctr, const uint32_t* __restrict__ list,
    uint32_t* __restrict__ qbits, uint32_t* __restrict__ kbits)
{
    const int lane = threadIdx.x & 63;
    const int wg = (blockIdx.x * blockDim.x + threadIdx.x) >> 6;
    const int nw = (gridDim.x * blockDim.x) >> 6;
    unsigned int n = *ctr; if (n > CAPQ) n = CAPQ;

    for (unsigned int i = wg; i < n; i += nw) {
        const uint32_t e = list[i];
        const int br = (e >> 23) & 1, o = (e >> 14) & 511, b = (e >> 10) & 15, hw = e & 1023;
        const float* w = (br ? kw : qw) + (size_t)o * CCH;
        double dots[TT];
#pragma unroll
        for (int t = 0; t < TT; ++t) {
            double s = 0.0;
            for (int c = lane; c < CCH; c += 64)
                s += (double)w[c] * (double)x[((size_t)(t * BB + b) * CCH + c) * HWD + hw];
#pragma unroll
            for (int off = 32; off; off >>= 1) s += __shfl_xor(s, off);
            dots[t] = s;
        }
        if (lane == 0) {
            const float* g  = br ? kg  : qg;
            const float* be = br ? kbe : qbe;
            const float* mn = br ? km  : qm;
            const float* va = br ? kva : qva;
            const double inv = (double)g[o] / sqrt((double)va[o] + 1e-5);
            const double add = (double)be[o] - (double)mn[o] * inv;
            uint32_t* bits = br ? kbits : qbits;
            double v = 0.0;
#pragma unroll
            for (int t = 0; t < TT; ++t) {
                const double y = dots[t] * inv + add;
                v = v + (y - v) * 0.5;
                const size_t wa = ((size_t)(t * BB + b) * NW + (o >> 5)) * HWD + hw;
                const uint32_t bit = 1u << (o & 31);
                if (v >= 1.0) { atomicOr(&bits[wa], bit); v = 0.0; }
                else          { atomicAnd(&bits[wa], ~bit); }
            }
        }
    }
}

// ---------------------------------------------------------------------------
// Kernel 3: head-sum of q spikes (popcount) + LIF at 0.5 (exact dyadic).
// ---------------------------------------------------------------------------
__global__ __launch_bounds__(256) void k_attn(
    const uint32_t* __restrict__ qbits, uint8_t* __restrict__ attn)
{
    const int idx = blockIdx.x * 256 + threadIdx.x;
    const int hw = idx & (HWD - 1);
    const int h  = (idx >> 10) & (NHH - 1);
    const int b  = idx >> 13;
    double v = 0.0;
#pragma unroll
    for (int t = 0; t < TT; ++t) {
        const uint32_t w0 = qbits[((size_t)(t * BB + b) * NW + h * 2    ) * HWD + hw];
        const uint32_t w1 = qbits[((size_t)(t * BB + b) * NW + h * 2 + 1) * HWD + hw];
        const double q = (double)(__popc(w0) + __popc(w1));
        v = v + (q - v) * 0.5;
        const uint8_t s = (v >= 0.5) ? (uint8_t)1 : (uint8_t)0;
        attn[((size_t)(t * BB + b) * NHH + h) * HWD + hw] = s;
        if (s) v = 0.0;
    }
}

// ---------------------------------------------------------------------------
// Kernel 4: proj conv via bf16 MFMA over binary y = attn & k (exact in bf16;
// W split -> 2 terms) + fp64 bias/BN/LIF + flags. Block = 128o x 32hw,
// 4 waves (2o x 2hw), wave = 64o x 16hw.
// ---------------------------------------------------------------------------
__global__ __launch_bounds__(256) void k_proj(
    const float* __restrict__ pw, const float* __restrict__ pb,
    const float* __restrict__ pg, const float* __restrict__ pbe,
    const float* __restrict__ pm, const float* __restrict__ pva,
    const uint32_t* __restrict__ kbits, const uint8_t* __restrict__ attn,
    float* __restrict__ out,
    unsigned int* __restrict__ ctr2, uint32_t* __restrict__ list2)
{
    const int tid = threadIdx.x, lane = tid & 63, wid = tid >> 6;
    const int b   = blockIdx.z;
    const int o0  = blockIdx.y * 128, hw0 = blockIdx.x * 32;
    const int worow = (wid >> 1) * 64, whw = (wid & 1) * 16;

    int rowD[4], colD[4], aRow, aKb, bCol, bKb;
    probe_bf16(lane, rowD, colD, aRow, aKb, bCol, bKb);
    const int hwB = hw0 + whw + bCol;

    f32x4 acc[TT][4];
#pragma unroll
    for (int t = 0; t < TT; ++t)
#pragma unroll
        for (int ot = 0; ot < 4; ++ot) acc[t][ot] = (f32x4){0.f, 0.f, 0.f, 0.f};

#pragma unroll 1
    for (int ks = 0; ks < 16; ++ks) {
        const int c0 = ks * 32;
        s16x8 Ah[4], Al[4];
#pragma unroll
        for (int ot = 0; ot < 4; ++ot)
            load_split_frag(pw + (size_t)(o0 + worow + ot * 16 + aRow) * CCH + c0 + aKb,
                            Ah[ot], Al[ot]);
#pragma unroll
        for (int t = 0; t < TT; ++t) {
            const size_t tb = (size_t)(t * BB + b);
            const uint32_t kv = kbits[(tb * NW + ks) * HWD + hwB];
            const uint32_t av = attn[(tb * NHH + (ks >> 1)) * HWD + hwB];
            const uint32_t mask = av ? kv : 0u;
            const uint32_t byt = (mask >> bKb) & 0xFFu;
            u32x4 bw;
#pragma unroll
            for (int j = 0; j < 4; ++j)
                bw[j] = (((byt >> (2 * j)) & 1u) ? 0x3F80u : 0u)
                      | (((byt >> (2 * j + 1)) & 1u) ? 0x3F800000u : 0u);
            const s16x8 By = __builtin_bit_cast(s16x8, bw);
#pragma unroll
            for (int ot = 0; ot < 4; ++ot) {
                acc[t][ot] = MFMA(Ah[ot], By, acc[t][ot]);
                acc[t][ot] = MFMA(Al[ot], By, acc[t][ot]);
            }
        }
    }

    // ---- epilogue: fp64 bias + BN + LIF + store + flags ----
#pragma unroll
    for (int ot = 0; ot < 4; ++ot)
#pragma unroll
        for (int r = 0; r < 4; ++r) {
            const int o = o0 + worow + ot * 16 + rowD[r];
            const int hwD = hw0 + whw + colD[r];
            const double inv = (double)pg[o] / sqrt((double)pva[o] + 1e-5);
            const double add = (double)pbe[o] - (double)pm[o] * inv;
            const double bias = (double)pb[o];
            double v = 0.0; bool fl = false;
#pragma unroll
            for (int t = 0; t < TT; ++t) {
                const double y = ((double)acc[t][ot][r] + bias) * inv + add;
                v = v + (y - v) * 0.5;
                if (fabs(v - 1.0) < MPROJ) fl = true;
                float s;
                if (v >= 1.0) { s = 1.0f; v = 0.0; } else { s = 0.0f; }
                out[((size_t)(t * BB + b) * CCH + o) * HWD + hwD] = s;
            }
            if (fl) {
                const unsigned int idx = atomicAdd(ctr2, 1u);
                if (idx < CAPP) list2[idx] = (uint32_t)((o << 14) | (b << 10) | hwD);
            }
        }
}

// ---------------------------------------------------------------------------
// Kernel 5: exact fp64 recompute of flagged proj chains; patch d_out.
// ---------------------------------------------------------------------------
__global__ __launch_bounds__(256) void k_fix_proj(
    const float* __restrict__ pw, const float* __restrict__ pb,
    const float* __restrict__ pg, const float* __restrict__ pbe,
    const float* __restrict__ pm, const float* __restrict__ pva,
    const uint32_t* __restrict__ kbits, const uint8_t* __restrict__ attn,
    const unsigned int* __restrict__ ctr2, const uint32_t* __restrict__ list2,
    float* __restrict__ out)
{
    const int lane = threadIdx.x & 63;
    const int wg = (blockIdx.x * blockDim.x + threadIdx.x) >> 6;
    const int nw = (gridDim.x * blockDim.x) >> 6;
    unsigned int n = *ctr2; if (n > CAPP) n = CAPP;

    for (unsigned int i = wg; i < n; i += nw) {
        const uint32_t e = list2[i];
        const int o = (e >> 14) & 511, b = (e >> 10) & 15, hw = e & 1023;
        const float* w = pw + (size_t)o * CCH;
        double dots[TT];
#pragma unroll
        for (int t = 0; t < TT; ++t) {
            double s = 0.0;
            for (int c = lane; c < CCH; c += 64) {
                const uint32_t kv = kbits[((size_t)(t * BB + b) * NW + (c >> 5)) * HWD + hw];
                const uint32_t av = attn[((size_t)(t * BB + b) * NHH + (c >> 6)) * HWD + hw];
                if (av && ((kv >> (c & 31)) & 1u)) s += (double)w[c];
            }
#pragma unroll
            for (int off = 32; off; off >>= 1) s += __shfl_xor(s, off);
            dots[t] = s;
        }
        if (lane == 0) {
            const double inv = (double)pg[o] / sqrt((double)pva[o] + 1e-5);
            const double add = (double)pbe[o] - (double)pm[o] * inv;
            const double bias = (double)pb[o];
            double v = 0.0;
#pragma unroll
            for (int t = 0; t < TT; ++t) {
                const double y = (dots[t] + bias) * inv + add;
                v = v + (y - v) * 0.5;
                float s;
                if (v >= 1.0) { s = 1.0f; v = 0.0; } else { s = 0.0f; }
                out[((size_t)(t * BB + b) * CCH + o) * HWD + hw] = s;
            }
        }
    }
}

extern "C" void kernel_launch(void* const* d_in, const int* in_sizes, int n_in,
                              void* d_out, int out_size, void* d_ws, size_t ws_size,
                              hipStream_t stream)
{
    (void)in_sizes; (void)n_in; (void)out_size; (void)ws_size;

    const float* x   = (const float*)d_in[0];
    const float* qw  = (const float*)d_in[1];
    const float* qg  = (const float*)d_in[2];
    const float* qbe = (const float*)d_in[3];
    const float* qm  = (const float*)d_in[4];
    const float* qv  = (const float*)d_in[5];
    const float* kw  = (const float*)d_in[6];
    const float* kg  = (const float*)d_in[7];
    const float* kbe = (const float*)d_in[8];
    const float* km  = (const float*)d_in[9];
    const float* kv  = (const float*)d_in[10];
    const float* pw  = (const float*)d_in[11];
    const float* pb  = (const float*)d_in[12];
    const float* pg  = (const float*)d_in[13];
    const float* pbe = (const float*)d_in[14];
    const float* pm  = (const float*)d_in[15];
    const float* pv  = (const float*)d_in[16];

    uint8_t* base = (uint8_t*)d_ws;
    uint32_t* qbits = (uint32_t*)base;                              // 4 MiB
    uint32_t* kbits = (uint32_t*)(base + 4194304);                  // 4 MiB
    uint8_t*  attn  = base + 8388608;                               // 512 KiB
    unsigned int* ctr = (unsigned int*)(base + 8912896);            // 256 B
    uint32_t* qklist  = (uint32_t*)(base + 8913152);                // 192 KiB
    uint32_t* prlist  = (uint32_t*)(base + 8913152 + CAPQ * 4);     // 64 KiB
    float* out = (float*)d_out;

    k_zero<<<1, 64, 0, stream>>>(ctr);
    k_qk<<<dim3(HWD / 32, CCH / 64, BB), 256, 0, stream>>>(
        x, qw, qg, qbe, qm, qv, kw, kg, kbe, km, kv, qbits, kbits, ctr, qklist);
    k_fix_qk<<<256, 256, 0, stream>>>(x, qw, qg, qbe, qm, qv,
                                      kw, kg, kbe, km, kv, ctr, qklist, qbits, kbits);
    k_attn<<<(BB * NHH * HWD) / 256, 256, 0, stream>>>(qbits, attn);
    k_proj<<<dim3(HWD / 32, CCH / 128, BB), 256, 0, stream>>>(
        pw, pb, pg, pbe, pm, pv, kbits, attn, out, ctr + 1, prlist);
    k_fix_proj<<<64, 256, 0, stream>>>(pw, pb, pg, pbe, pm, pv,
                                       kbits, attn, ctr + 1, prlist, out);
}

// Round 8
// 560.515 us; speedup vs baseline: 6.0371x; 1.4505x over previous
//
#include <hip/hip_runtime.h>
#include <cstdint>
#include <math.h>

#define TT 4
#define BB 16
#define CCH 512
#define HWD 1024
#define NHH 8
#define NW 16            // 512/32 channel bit-words
#define MQK 1.5e-4       // flag margin q/k (error std ~1.5e-5 -> 10 sigma)
#define MPROJ 1.0e-4     // flag margin proj
#define CAPQ 49152
#define CAPP 16384
#define WTSZ 262144      // ushorts per (mat,hi/lo) tile array: 32*16*64*8

typedef __attribute__((ext_vector_type(4))) float f32x4;
typedef __attribute__((ext_vector_type(8))) short s16x8;
typedef __attribute__((ext_vector_type(4))) uint32_t u32x4;

static __device__ __forceinline__ f32x4 MFMA(s16x8 a, s16x8 b, f32x4 c) {
    return __builtin_amdgcn_mfma_f32_16x16x32_bf16(a, b, c, 0, 0, 0);
}

// pack the two high halves (bf16 truncations) of u0,u1 into one u32
static __device__ __forceinline__ uint32_t hi_pair(uint32_t u0, uint32_t u1) {
#if __has_builtin(__builtin_amdgcn_perm)
    return __builtin_amdgcn_perm(u1, u0, 0x07060302u);
#else
    return (u1 & 0xFFFF0000u) | (u0 >> 16);
#endif
}

struct SplitPair { uint32_t h, l; };

// truncation split: x = bf(h) + bf(l) + r, |r| <= 2^-15 |x|
static __device__ __forceinline__ SplitPair split_pair(float f0, float f1) {
    const uint32_t u0 = __builtin_bit_cast(uint32_t, f0);
    const uint32_t u1 = __builtin_bit_cast(uint32_t, f1);
    SplitPair r;
    r.h = hi_pair(u0, u1);
    const float r0 = f0 - __builtin_bit_cast(float, u0 & 0xFFFF0000u);
    const float r1 = f1 - __builtin_bit_cast(float, u1 & 0xFFFF0000u);
    r.l = hi_pair(__builtin_bit_cast(uint32_t, r0), __builtin_bit_cast(uint32_t, r1));
    return r;
}

static __device__ __forceinline__ void split_frag8(const float f[8], s16x8& h, s16x8& l) {
    u32x4 hw_, lw_;
    const SplitPair p0 = split_pair(f[0], f[1]);
    const SplitPair p1 = split_pair(f[2], f[3]);
    const SplitPair p2 = split_pair(f[4], f[5]);
    const SplitPair p3 = split_pair(f[6], f[7]);
    hw_[0] = p0.h; lw_[0] = p0.l;
    hw_[1] = p1.h; lw_[1] = p1.l;
    hw_[2] = p2.h; lw_[2] = p2.l;
    hw_[3] = p3.h; lw_[3] = p3.l;
    h = __builtin_bit_cast(s16x8, hw_);
    l = __builtin_bit_cast(s16x8, lw_);
}

static __device__ __forceinline__ void load_split_frag(const float* p, s16x8& h, s16x8& l) {
    const float4 a = *(const float4*)p;
    const float4 b4 = *(const float4*)(p + 4);
    const float f[8] = {a.x, a.y, a.z, a.w, b4.x, b4.y, b4.z, b4.w};
    split_frag8(f, h, l);
}

// ---------------------------------------------------------------------------
// Layout self-probe for mfma_f32_16x16x32_bf16 (see R6 — verified on HW).
// ---------------------------------------------------------------------------
static __device__ __forceinline__ void probe_bf16(int lane, int rowD[4], int colD[4],
                                                  int& aRow, int& aKb, int& bCol, int& bKb)
{
    const f32x4 z = {0.f, 0.f, 0.f, 0.f};
    const short lv = (short)(__builtin_bit_cast(uint32_t, (float)lane) >> 16);
    const short one = (short)0x3F80;
    const s16x8 av = {lv, lv, lv, lv, lv, lv, lv, lv};
    const s16x8 ov = {one, one, one, one, one, one, one, one};
    const f32x4 pa = MFMA(av, ov, z);
    const f32x4 pb = MFMA(ov, av, z);
    bool A2 = false, B2 = false;
#pragma unroll
    for (int r = 0; r < 4; ++r) {
        const int va = (int)pa[r];
        if (((va - 48) & 127) == 0) { rowD[r] = (va - 48) >> 7; A2 = true; }
        else                        { rowD[r] = (va - 768) >> 5; }
        const int vb = (int)pb[r];
        if (((vb - 48) & 127) == 0) { colD[r] = (vb - 48) >> 7; B2 = true; }
        else                        { colD[r] = (vb - 768) >> 5; }
    }
    aRow = A2 ? (lane >> 2) : (lane & 15);
    aKb  = A2 ? (lane & 3) * 8 : (lane >> 4) * 8;
    bCol = B2 ? (lane >> 2) : (lane & 15);
    bKb  = B2 ? (lane & 3) * 8 : (lane >> 4) * 8;
}

__global__ void k_zero(unsigned int* ctr) {
    if (threadIdx.x < 2) ctr[threadIdx.x] = 0u;
}

// ---------------------------------------------------------------------------
// Pre-pass: split q/k/proj weights into canonical MFMA-frag hi/lo tiles:
//   wt[(mat*2+hl)*WTSZ + ((ot*16+ks)*64 + kgrp*16 + row)*8 + e]
// and precompute fp64 BN constants (proj bias folded into add).
// ---------------------------------------------------------------------------
__global__ __launch_bounds__(256) void k_prep(
    const float* __restrict__ qw, const float* __restrict__ kw, const float* __restrict__ pw,
    const float* __restrict__ qg, const float* __restrict__ qbe,
    const float* __restrict__ qm, const float* __restrict__ qva,
    const float* __restrict__ kg, const float* __restrict__ kbe,
    const float* __restrict__ km, const float* __restrict__ kva,
    const float* __restrict__ pg, const float* __restrict__ pbe,
    const float* __restrict__ pm, const float* __restrict__ pva,
    const float* __restrict__ pb,
    unsigned short* __restrict__ wt, double* __restrict__ bnc)
{
    const int bx = blockIdx.x;        // 0..95
    const int mat = bx >> 5, ot = bx & 31;
    const float* W = (mat == 0) ? qw : ((mat == 1) ? kw : pw);
    unsigned short* hi = wt + (size_t)(mat * 2 + 0) * WTSZ;
    unsigned short* lo = wt + (size_t)(mat * 2 + 1) * WTSZ;
#pragma unroll
    for (int it = 0; it < 4; ++it) {
        const int j = it * 256 + threadIdx.x;   // 0..1023 chunk index
        const int ks = j >> 6, sub = j & 63;
        const int kgrp = sub >> 4, row = sub & 15;
        const float* src = W + (size_t)(ot * 16 + row) * CCH + ks * 32 + kgrp * 8;
        s16x8 h, l;
        load_split_frag(src, h, l);
        *(s16x8*)&hi[((size_t)(ot * 16 + ks) * 64 + sub) * 8] = h;
        *(s16x8*)&lo[((size_t)(ot * 16 + ks) * 64 + sub) * 8] = l;
    }
    if (ot == 0) {
        const float* g  = (mat == 0) ? qg  : ((mat == 1) ? kg  : pg);
        const float* be = (mat == 0) ? qbe : ((mat == 1) ? kbe : pbe);
        const float* mn = (mat == 0) ? qm  : ((mat == 1) ? km  : pm);
        const float* va = (mat == 0) ? qva : ((mat == 1) ? kva : pva);
        for (int o = threadIdx.x; o < CCH; o += 256) {
            const double inv = (double)g[o] / sqrt((double)va[o] + 1e-5);
            double add = (double)be[o] - (double)mn[o] * inv;
            if (mat == 2) add = add + (double)pb[o] * inv;
            bnc[(size_t)(mat * CCH + o) * 2]     = inv;
            bnc[(size_t)(mat * CCH + o) * 2 + 1] = add;
        }
    }
}

// ---------------------------------------------------------------------------
// Kernel: q/k conv1x1 via bf16-split MFMA (3 cross terms), A from pre-split
// tiles (coalesced), X staged in LDS with XOR bank swizzle, fp64 BN/LIF,
// spikes bitpacked, near-threshold chains flagged.
// Block = 64o x 32hw, 4 waves (2o x 2hw), wave = 32o x 16hw, both branches.
// ---------------------------------------------------------------------------
__global__ __launch_bounds__(256) void k_qk(
    const float* __restrict__ x, const unsigned short* __restrict__ wt,
    const double* __restrict__ bnc,
    uint32_t* __restrict__ qbits, uint32_t* __restrict__ kbits,
    unsigned int* __restrict__ ctr, uint32_t* __restrict__ list)
{
    __shared__ float Xs[4096];              // [t][c 32][hw-phys 32], swizzled
    __shared__ uint32_t QB[2][2][TT][32];   // [branch][o-word][t][hw]

    const int tid = threadIdx.x, lane = tid & 63, wid = tid >> 6;
    const int b   = blockIdx.z;
    const int o0  = blockIdx.y * 64, hw0 = blockIdx.x * 32;
    const int worow = (wid >> 1) * 32, whw = (wid & 1) * 16;

    int rowD[4], colD[4], aRow, aKb, bCol, bKb;
    probe_bf16(lane, rowD, colD, aRow, aKb, bCol, bKb);

    // A-frag offset within a [64][8] k-step tile (canonical order)
    const int laneoff = ((aKb >> 3) * 16 + aRow) * 8;
    const int kgrp = bKb >> 3;
    const int hwl  = whw + bCol;                 // logical hw within tile
    const int xoff = (((hwl >> 2) ^ (kgrp << 1)) << 2) + (hwl & 3);
    const int otg0 = blockIdx.y * 4 + (wid >> 1) * 2;   // first 16-o tile idx

    // staging decomposition (per thread, constant across ks)
    int sT[4], sC[4], sHw4[4], sDst[4];
#pragma unroll
    for (int it = 0; it < 4; ++it) {
        const int j = it * 256 + tid;       // 0..1023 16B chunks
        sT[it] = j >> 8; sC[it] = (j >> 3) & 31; sHw4[it] = j & 7;
        sDst[it] = sT[it] * 1024 + sC[it] * 32 + ((sHw4[it] ^ ((sC[it] >> 3) << 1)) << 2);
    }

    f32x4 aq[TT][2], ak[TT][2];
#pragma unroll
    for (int t = 0; t < TT; ++t)
#pragma unroll
        for (int ot = 0; ot < 2; ++ot) {
            aq[t][ot] = (f32x4){0.f, 0.f, 0.f, 0.f};
            ak[t][ot] = (f32x4){0.f, 0.f, 0.f, 0.f};
        }

    float4 st[4];
#pragma unroll
    for (int it = 0; it < 4; ++it)
        st[it] = *(const float4*)&x[((size_t)(sT[it] * BB + b) * CCH + sC[it]) * HWD
                                    + hw0 + sHw4[it] * 4];
#pragma unroll
    for (int it = 0; it < 4; ++it) *(float4*)&Xs[sDst[it]] = st[it];
    __syncthreads();

#pragma unroll 1
    for (int ks = 0; ks < 16; ++ks) {
        if (ks < 15) {
#pragma unroll
            for (int it = 0; it < 4; ++it)
                st[it] = *(const float4*)&x[((size_t)(sT[it] * BB + b) * CCH
                                             + (ks + 1) * 32 + sC[it]) * HWD
                                            + hw0 + sHw4[it] * 4];
        }
        // A-fragment loads from pre-split tiles (coalesced 16B)
        s16x8 Aqh[2], Aql[2], Akh[2], Akl[2];
#pragma unroll
        for (int ot = 0; ot < 2; ++ot) {
            const size_t tb = ((size_t)(otg0 + ot) * 16 + ks) * 512 + laneoff;
            Aqh[ot] = *(const s16x8*)&wt[0 * WTSZ + tb];
            Aql[ot] = *(const s16x8*)&wt[1 * WTSZ + tb];
            Akh[ot] = *(const s16x8*)&wt[2 * WTSZ + tb];
            Akl[ot] = *(const s16x8*)&wt[3 * WTSZ + tb];
        }
#pragma unroll
        for (int t = 0; t < TT; ++t) {
            float f[8];
#pragma unroll
            for (int e = 0; e < 8; ++e)
                f[e] = Xs[t * 1024 + (kgrp * 8 + e) * 32 + xoff];
            s16x8 Bh, Bl;
            split_frag8(f, Bh, Bl);
#pragma unroll
            for (int ot = 0; ot < 2; ++ot) {
                aq[t][ot] = MFMA(Aqh[ot], Bh, aq[t][ot]);
                aq[t][ot] = MFMA(Aqh[ot], Bl, aq[t][ot]);
                aq[t][ot] = MFMA(Aql[ot], Bh, aq[t][ot]);
                ak[t][ot] = MFMA(Akh[ot], Bh, ak[t][ot]);
                ak[t][ot] = MFMA(Akh[ot], Bl, ak[t][ot]);
                ak[t][ot] = MFMA(Akl[ot], Bh, ak[t][ot]);
            }
        }
        __syncthreads();
        if (ks < 15) {
#pragma unroll
            for (int it = 0; it < 4; ++it) *(float4*)&Xs[sDst[it]] = st[it];
        }
        __syncthreads();
    }

    // ---- epilogue: fp64 BN + LIF, flags, bitpack ----
    ((uint32_t*)QB)[tid] = 0u;
    ((uint32_t*)QB)[tid + 256] = 0u;
    __syncthreads();

    auto chains = [&](f32x4 (&acc)[TT][2], int br) {
#pragma unroll
        for (int ot = 0; ot < 2; ++ot)
#pragma unroll
            for (int r = 0; r < 4; ++r) {
                const int orow = worow + ot * 16 + rowD[r];    // 0..63
                const int o = o0 + orow;
                const double inv = bnc[(size_t)(br * CCH + o) * 2];
                const double add = bnc[(size_t)(br * CCH + o) * 2 + 1];
                const uint32_t bit = 1u << (orow & 31);
                const int ow = orow >> 5;
                const int hwq = whw + colD[r];
                double v = 0.0; bool fl = false;
#pragma unroll
                for (int t = 0; t < TT; ++t) {
                    const double y = (double)acc[t][ot][r] * inv + add;
                    v = v + (y - v) * 0.5;
                    if (fabs(v - 1.0) < MQK) fl = true;
                    if (v >= 1.0) { atomicOr(&QB[br][ow][t][hwq], bit); v = 0.0; }
                }
                if (fl) {
                    const unsigned int idx = atomicAdd(ctr, 1u);
                    if (idx < CAPQ)
                        list[idx] = (uint32_t)((br << 23) | (o << 14) | (b << 10) | (hw0 + hwq));
                }
            }
    };
    chains(aq, 0);
    chains(ak, 1);
    __syncthreads();

#pragma unroll
    for (int u = 0; u < 2; ++u) {
        const int idx = tid + u * 256;   // 0..511
        const int br = idx >> 8, ow = (idx >> 7) & 1, t = (idx >> 5) & 3, hwq = idx & 31;
        uint32_t* dst = br ? kbits : qbits;
        dst[((size_t)(t * BB + b) * NW + (o0 >> 5) + ow) * HWD + hw0 + hwq] = QB[br][ow][t][hwq];
    }
}

// ---------------------------------------------------------------------------
// Exact fp64 recompute of flagged q/k chains; patch spike bits.
// ---------------------------------------------------------------------------
__global__ __launch_bounds__(256) void k_fix_qk(
    const float* __restrict__ x,
    const float* __restrict__ qw, const float* __restrict__ qg, const float* __restrict__ qbe,
    const float* __restrict__ qm, const float* __restrict__ qva,
    const float* __restrict__ kw, const float* __restrict__ kg, const float* __restrict__ kbe,
    const float* __restrict__ km, const float* __restrict__ kva,
    const unsigned int* __restrict__ ctr, const uint32_t* __restrict__ list,
    uint32_t* __restrict__ qbits, uint32_t* __restrict__ kbits)
{
    const int lane = threadIdx.x & 63;
    const int wg = (blockIdx.x * blockDim.x + threadIdx.x) >> 6;
    const int nw = (gridDim.x * blockDim.x) >> 6;
    unsigned int n = *ctr; if (n > CAPQ) n = CAPQ;

    for (unsigned int i = wg; i < n; i += nw) {
        const uint32_t e = list[i];
        const int br = (e >> 23) & 1, o = (e >> 14) & 511, b = (e >> 10) & 15, hw = e & 1023;
        const float* w = (br ? kw : qw) + (size_t)o * CCH;
        double dots[TT];
#pragma unroll
        for (int t = 0; t < TT; ++t) {
            double s = 0.0;
            for (int c = lane; c < CCH; c += 64)
                s += (double)w[c] * (double)x[((size_t)(t * BB + b) * CCH + c) * HWD + hw];
#pragma unroll
            for (int off = 32; off; off >>= 1) s += __shfl_xor(s, off);
            dots[t] = s;
        }
        if (lane == 0) {
            const float* g  = br ? kg  : qg;
            const float* be = br ? kbe : qbe;
            const float* mn = br ? km  : qm;
            const float* va = br ? kva : qva;
            const double inv = (double)g[o] / sqrt((double)va[o] + 1e-5);
            const double add = (double)be[o] - (double)mn[o] * inv;
            uint32_t* bits = br ? kbits : qbits;
            double v = 0.0;
#pragma unroll
            for (int t = 0; t < TT; ++t) {
                const double y = dots[t] * inv + add;
                v = v + (y - v) * 0.5;
                const size_t wa = ((size_t)(t * BB + b) * NW + (o >> 5)) * HWD + hw;
                const uint32_t bit = 1u << (o & 31);
                if (v >= 1.0) { atomicOr(&bits[wa], bit); v = 0.0; }
                else          { atomicAnd(&bits[wa], ~bit); }
            }
        }
    }
}

// ---------------------------------------------------------------------------
// Head-sum of q spikes (popcount) + LIF at 0.5 (exact dyadic).
// ---------------------------------------------------------------------------
__global__ __launch_bounds__(256) void k_attn(
    const uint32_t* __restrict__ qbits, uint8_t* __restrict__ attn)
{
    const int idx = blockIdx.x * 256 + threadIdx.x;
    const int hw = idx & (HWD - 1);
    const int h  = (idx >> 10) & (NHH - 1);
    const int b  = idx >> 13;
    double v = 0.0;
#pragma unroll
    for (int t = 0; t < TT; ++t) {
        const uint32_t w0 = qbits[((size_t)(t * BB + b) * NW + h * 2    ) * HWD + hw];
        const uint32_t w1 = qbits[((size_t)(t * BB + b) * NW + h * 2 + 1) * HWD + hw];
        const double q = (double)(__popc(w0) + __popc(w1));
        v = v + (q - v) * 0.5;
        const uint8_t s = (v >= 0.5) ? (uint8_t)1 : (uint8_t)0;
        attn[((size_t)(t * BB + b) * NHH + h) * HWD + hw] = s;
        if (s) v = 0.0;
    }
}

// ---------------------------------------------------------------------------
// proj conv via bf16 MFMA over binary y = attn & k (exact in bf16; A from
// pre-split tiles -> 2 terms) + fp64 bias/BN/LIF + flags.
// Block = 128o x 32hw, 4 waves (2o x 2hw), wave = 64o x 16hw.
// ---------------------------------------------------------------------------
__global__ __launch_bounds__(256) void k_proj(
    const unsigned short* __restrict__ wt, const double* __restrict__ bnc,
    const uint32_t* __restrict__ kbits, const uint8_t* __restrict__ attn,
    float* __restrict__ out,
    unsigned int* __restrict__ ctr2, uint32_t* __restrict__ list2)
{
    const int tid = threadIdx.x, lane = tid & 63, wid = tid >> 6;
    const int b   = blockIdx.z;
    const int o0  = blockIdx.y * 128, hw0 = blockIdx.x * 32;
    const int worow = (wid >> 1) * 64, whw = (wid & 1) * 16;

    int rowD[4], colD[4], aRow, aKb, bCol, bKb;
    probe_bf16(lane, rowD, colD, aRow, aKb, bCol, bKb);
    const int laneoff = ((aKb >> 3) * 16 + aRow) * 8;
    const int hwB = hw0 + whw + bCol;
    const int otg0 = blockIdx.y * 8 + (wid >> 1) * 4;

    f32x4 acc[TT][4];
#pragma unroll
    for (int t = 0; t < TT; ++t)
#pragma unroll
        for (int ot = 0; ot < 4; ++ot) acc[t][ot] = (f32x4){0.f, 0.f, 0.f, 0.f};

#pragma unroll 1
    for (int ks = 0; ks < 16; ++ks) {
        s16x8 Ah[4], Al[4];
#pragma unroll
        for (int ot = 0; ot < 4; ++ot) {
            const size_t tb = ((size_t)(otg0 + ot) * 16 + ks) * 512 + laneoff;
            Ah[ot] = *(const s16x8*)&wt[4 * WTSZ + tb];
            Al[ot] = *(const s16x8*)&wt[5 * WTSZ + tb];
        }
#pragma unroll
        for (int t = 0; t < TT; ++t) {
            const size_t tb = (size_t)(t * BB + b);
            const uint32_t kv = kbits[(tb * NW + ks) * HWD + hwB];
            const uint32_t av = attn[(tb * NHH + (ks >> 1)) * HWD + hwB];
            const uint32_t mask = av ? kv : 0u;
            const uint32_t byt = (mask >> bKb) & 0xFFu;
            u32x4 bw;
#pragma unroll
            for (int j = 0; j < 4; ++j)
                bw[j] = (((byt >> (2 * j)) & 1u) ? 0x3F80u : 0u)
                      | (((byt >> (2 * j + 1)) & 1u) ? 0x3F800000u : 0u);
            const s16x8 By = __builtin_bit_cast(s16x8, bw);
#pragma unroll
            for (int ot = 0; ot < 4; ++ot) {
                acc[t][ot] = MFMA(Ah[ot], By, acc[t][ot]);
                acc[t][ot] = MFMA(Al[ot], By, acc[t][ot]);
            }
        }
    }

    // ---- epilogue: fp64 BN (bias folded) + LIF + store + flags ----
#pragma unroll
    for (int ot = 0; ot < 4; ++ot)
#pragma unroll
        for (int r = 0; r < 4; ++r) {
            const int o = o0 + worow + ot * 16 + rowD[r];
            const int hwD = hw0 + whw + colD[r];
            const double inv = bnc[(size_t)(2 * CCH + o) * 2];
            const double add = bnc[(size_t)(2 * CCH + o) * 2 + 1];
            double v = 0.0; bool fl = false;
#pragma unroll
            for (int t = 0; t < TT; ++t) {
                const double y = (double)acc[t][ot][r] * inv + add;
                v = v + (y - v) * 0.5;
                if (fabs(v - 1.0) < MPROJ) fl = true;
                float s;
                if (v >= 1.0) { s = 1.0f; v = 0.0; } else { s = 0.0f; }
                out[((size_t)(t * BB + b) * CCH + o) * HWD + hwD] = s;
            }
            if (fl) {
                const unsigned int idx = atomicAdd(ctr2, 1u);
                if (idx < CAPP) list2[idx] = (uint32_t)((o << 14) | (b << 10) | hwD);
            }
        }
}

// ---------------------------------------------------------------------------
// Exact fp64 recompute of flagged proj chains; patch d_out.
// ---------------------------------------------------------------------------
__global__ __launch_bounds__(256) void k_fix_proj(
    const float* __restrict__ pw, const float* __restrict__ pb,
    const float* __restrict__ pg, const float* __restrict__ pbe,
    const float* __restrict__ pm, const float* __restrict__ pva,
    const uint32_t* __restrict__ kbits, const uint8_t* __restrict__ attn,
    const unsigned int* __restrict__ ctr2, const uint32_t* __restrict__ list2,
    float* __restrict__ out)
{
    const int lane = threadIdx.x & 63;
    const int wg = (blockIdx.x * blockDim.x + threadIdx.x) >> 6;
    const int nw = (gridDim.x * blockDim.x) >> 6;
    unsigned int n = *ctr2; if (n > CAPP) n = CAPP;

    for (unsigned int i = wg; i < n; i += nw) {
        const uint32_t e = list2[i];
        const int o = (e >> 14) & 511, b = (e >> 10) & 15, hw = e & 1023;
        const float* w = pw + (size_t)o * CCH;
        double dots[TT];
#pragma unroll
        for (int t = 0; t < TT; ++t) {
            double s = 0.0;
            for (int c = lane; c < CCH; c += 64) {
                const uint32_t kv = kbits[((size_t)(t * BB + b) * NW + (c >> 5)) * HWD + hw];
                const uint32_t av = attn[((size_t)(t * BB + b) * NHH + (c >> 6)) * HWD + hw];
                if (av && ((kv >> (c & 31)) & 1u)) s += (double)w[c];
            }
#pragma unroll
            for (int off = 32; off; off >>= 1) s += __shfl_xor(s, off);
            dots[t] = s;
        }
        if (lane == 0) {
            const double inv = (double)pg[o] / sqrt((double)pva[o] + 1e-5);
            const double add = (double)pbe[o] - (double)pm[o] * inv;
            const double bias = (double)pb[o];
            double v = 0.0;
#pragma unroll
            for (int t = 0; t < TT; ++t) {
                const double y = (dots[t] + bias) * inv + add;
                v = v + (y - v) * 0.5;
                float s;
                if (v >= 1.0) { s = 1.0f; v = 0.0; } else { s = 0.0f; }
                out[((size_t)(t * BB + b) * CCH + o) * HWD + hw] = s;
            }
        }
    }
}

extern "C" void kernel_launch(void* const* d_in, const int* in_sizes, int n_in,
                              void* d_out, int out_size, void* d_ws, size_t ws_size,
                              hipStream_t stream)
{
    (void)in_sizes; (void)n_in; (void)out_size; (void)ws_size;

    const float* x   = (const float*)d_in[0];
    const float* qw  = (const float*)d_in[1];
    const float* qg  = (const float*)d_in[2];
    const float* qbe = (const float*)d_in[3];
    const float* qm  = (const float*)d_in[4];
    const float* qv  = (const float*)d_in[5];
    const float* kw  = (const float*)d_in[6];
    const float* kg  = (const float*)d_in[7];
    const float* kbe = (const float*)d_in[8];
    const float* km  = (const float*)d_in[9];
    const float* kv  = (const float*)d_in[10];
    const float* pw  = (const float*)d_in[11];
    const float* pb  = (const float*)d_in[12];
    const float* pg  = (const float*)d_in[13];
    const float* pbe = (const float*)d_in[14];
    const float* pm  = (const float*)d_in[15];
    const float* pv  = (const float*)d_in[16];

    uint8_t* base = (uint8_t*)d_ws;
    uint32_t* qbits = (uint32_t*)base;                              // 4 MiB
    uint32_t* kbits = (uint32_t*)(base + 4194304);                  // 4 MiB
    uint8_t*  attn  = base + 8388608;                               // 512 KiB
    unsigned int* ctr = (unsigned int*)(base + 8912896);            // 256 B
    uint32_t* qklist  = (uint32_t*)(base + 8913152);                // 192 KiB
    uint32_t* prlist  = (uint32_t*)(base + 9109760);                // 64 KiB
    unsigned short* wtiles = (unsigned short*)(base + 9175296);     // 3 MiB
    double* bnc = (double*)(base + 12321024);                       // 24 KiB
    float* out = (float*)d_out;

    k_zero<<<1, 64, 0, stream>>>(ctr);
    k_prep<<<96, 256, 0, stream>>>(qw, kw, pw, qg, qbe, qm, qv,
                                   kg, kbe, km, kv, pg, pbe, pm, pv, pb,
                                   wtiles, bnc);
    k_qk<<<dim3(HWD / 32, CCH / 64, BB), 256, 0, stream>>>(
        x, wtiles, bnc, qbits, kbits, ctr, qklist);
    k_fix_qk<<<256, 256, 0, stream>>>(x, qw, qg, qbe, qm, qv,
                                      kw, kg, kbe, km, kv, ctr, qklist, qbits, kbits);
    k_attn<<<(BB * NHH * HWD) / 256, 256, 0, stream>>>(qbits, attn);
    k_proj<<<dim3(HWD / 32, CCH / 128, BB), 256, 0, stream>>>(
        wtiles, bnc, kbits, attn, out, ctr + 1, prlist);
    k_fix_proj<<<64, 256, 0, stream>>>(pw, pb, pg, pbe, pm, pv,
                                       kbits, attn, ctr + 1, prlist, out);
}

// Round 9
// 463.788 us; speedup vs baseline: 7.2961x; 1.2086x over previous
//
#include <hip/hip_runtime.h>
#include <cstdint>
#include <math.h>

#define TT 4
#define BB 16
#define CCH 512
#define HWD 1024
#define NHH 8
#define NW 16            // 512/32 channel bit-words
#define MQK 1.5e-4       // flag margin q/k (error std ~1.5e-5 -> 10 sigma)
#define MPROJ 1.0e-4     // flag margin proj
#define CAPQ 49152
#define CAPP 16384
#define WTSZ 262144      // ushorts per (mat,hi/lo) tile array: 32*16*64*8
#define XSOFF 12345600ULL
#define XSBYTES 134217728ULL
#define WSNEED (XSOFF + XSBYTES)

typedef __attribute__((ext_vector_type(4))) float f32x4;
typedef __attribute__((ext_vector_type(8))) short s16x8;
typedef __attribute__((ext_vector_type(4))) uint32_t u32x4;

static __device__ __forceinline__ f32x4 MFMA(s16x8 a, s16x8 b, f32x4 c) {
    return __builtin_amdgcn_mfma_f32_16x16x32_bf16(a, b, c, 0, 0, 0);
}

// high halves of u0,u1 -> one u32 (elements (e0,e1) -> low|high)
static __device__ __forceinline__ uint32_t hi_pair(uint32_t u0, uint32_t u1) {
#if __has_builtin(__builtin_amdgcn_perm)
    return __builtin_amdgcn_perm(u1, u0, 0x07060302u);
#else
    return (u1 & 0xFFFF0000u) | (u0 >> 16);
#endif
}
// low halves of u0,u1 -> one u32
static __device__ __forceinline__ uint32_t lo_pair(uint32_t u0, uint32_t u1) {
#if __has_builtin(__builtin_amdgcn_perm)
    return __builtin_amdgcn_perm(u1, u0, 0x05040100u);
#else
    return ((u1 & 0xFFFFu) << 16) | (u0 & 0xFFFFu);
#endif
}

struct SplitPair { uint32_t h, l; };

// truncation split: x = bf(h) + bf(l) + r, |r| <= 2^-15 |x|
static __device__ __forceinline__ SplitPair split_pair(float f0, float f1) {
    const uint32_t u0 = __builtin_bit_cast(uint32_t, f0);
    const uint32_t u1 = __builtin_bit_cast(uint32_t, f1);
    SplitPair r;
    r.h = hi_pair(u0, u1);
    const float r0 = f0 - __builtin_bit_cast(float, u0 & 0xFFFF0000u);
    const float r1 = f1 - __builtin_bit_cast(float, u1 & 0xFFFF0000u);
    r.l = hi_pair(__builtin_bit_cast(uint32_t, r0), __builtin_bit_cast(uint32_t, r1));
    return r;
}

static __device__ __forceinline__ void load_split_frag(const float* p, s16x8& h, s16x8& l) {
    const float4 a = *(const float4*)p;
    const float4 b4 = *(const float4*)(p + 4);
    u32x4 hw_, lw_;
    const SplitPair p0 = split_pair(a.x, a.y);
    const SplitPair p1 = split_pair(a.z, a.w);
    const SplitPair p2 = split_pair(b4.x, b4.y);
    const SplitPair p3 = split_pair(b4.z, b4.w);
    hw_[0] = p0.h; lw_[0] = p0.l;
    hw_[1] = p1.h; lw_[1] = p1.l;
    hw_[2] = p2.h; lw_[2] = p2.l;
    hw_[3] = p3.h; lw_[3] = p3.l;
    h = __builtin_bit_cast(s16x8, hw_);
    l = __builtin_bit_cast(s16x8, lw_);
}

// pack one float -> (hi-bf16 << 16) | lo-bf16, truncation split
static __device__ __forceinline__ uint32_t packsplit(float f) {
    const uint32_t u = __builtin_bit_cast(uint32_t, f);
    const uint32_t hi = u & 0xFFFF0000u;
    const float r = f - __builtin_bit_cast(float, hi);
    return hi | (__builtin_bit_cast(uint32_t, r) >> 16);
}

// ---------------------------------------------------------------------------
// Layout self-probe for mfma_f32_16x16x32_bf16 (verified on HW in R6/R8).
// ---------------------------------------------------------------------------
static __device__ __forceinline__ void probe_bf16(int lane, int rowD[4], int colD[4],
                                                  int& aRow, int& aKb, int& bCol, int& bKb)
{
    const f32x4 z = {0.f, 0.f, 0.f, 0.f};
    const short lv = (short)(__builtin_bit_cast(uint32_t, (float)lane) >> 16);
    const short one = (short)0x3F80;
    const s16x8 av = {lv, lv, lv, lv, lv, lv, lv, lv};
    const s16x8 ov = {one, one, one, one, one, one, one, one};
    const f32x4 pa = MFMA(av, ov, z);
    const f32x4 pb = MFMA(ov, av, z);
    bool A2 = false, B2 = false;
#pragma unroll
    for (int r = 0; r < 4; ++r) {
        const int va = (int)pa[r];
        if (((va - 48) & 127) == 0) { rowD[r] = (va - 48) >> 7; A2 = true; }
        else                        { rowD[r] = (va - 768) >> 5; }
        const int vb = (int)pb[r];
        if (((vb - 48) & 127) == 0) { colD[r] = (vb - 48) >> 7; B2 = true; }
        else                        { colD[r] = (vb - 768) >> 5; }
    }
    aRow = A2 ? (lane >> 2) : (lane & 15);
    aKb  = A2 ? (lane & 3) * 8 : (lane >> 4) * 8;
    bCol = B2 ? (lane >> 2) : (lane & 15);
    bKb  = B2 ? (lane & 3) * 8 : (lane >> 4) * 8;
}

__global__ void k_zero(unsigned int* ctr) {
    if (threadIdx.x < 2) ctr[threadIdx.x] = 0u;
}

// ---------------------------------------------------------------------------
// Pre-split x into packed u32 (hi|lo bf16), same [tb][c][hw] layout as x.
// ---------------------------------------------------------------------------
__global__ __launch_bounds__(256) void k_xsplit(const float* __restrict__ x,
                                                uint32_t* __restrict__ xs)
{
    const size_t N = (size_t)TT * BB * CCH * HWD;
    size_t i = ((size_t)blockIdx.x * 256 + threadIdx.x) * 4;
    const size_t stride = (size_t)gridDim.x * 1024;
    for (; i < N; i += stride) {
        const float4 v = *(const float4*)&x[i];
        u32x4 p;
        p[0] = packsplit(v.x); p[1] = packsplit(v.y);
        p[2] = packsplit(v.z); p[3] = packsplit(v.w);
        *(u32x4*)&xs[i] = p;
    }
}

// ---------------------------------------------------------------------------
// Pre-pass: split q/k/proj weights into canonical MFMA-frag hi/lo tiles:
//   wt[(mat*2+hl)*WTSZ + ((ot*16+ks)*64 + kgrp*16 + row)*8 + e]
// and precompute fp64 BN constants (proj bias folded into add).
// ---------------------------------------------------------------------------
__global__ __launch_bounds__(256) void k_prep(
    const float* __restrict__ qw, const float* __restrict__ kw, const float* __restrict__ pw,
    const float* __restrict__ qg, const float* __restrict__ qbe,
    const float* __restrict__ qm, const float* __restrict__ qva,
    const float* __restrict__ kg, const float* __restrict__ kbe,
    const float* __restrict__ km, const float* __restrict__ kva,
    const float* __restrict__ pg, const float* __restrict__ pbe,
    const float* __restrict__ pm, const float* __restrict__ pva,
    const float* __restrict__ pb,
    unsigned short* __restrict__ wt, double* __restrict__ bnc)
{
    const int bx = blockIdx.x;        // 0..95
    const int mat = bx >> 5, ot = bx & 31;
    const float* W = (mat == 0) ? qw : ((mat == 1) ? kw : pw);
    unsigned short* hi = wt + (size_t)(mat * 2 + 0) * WTSZ;
    unsigned short* lo = wt + (size_t)(mat * 2 + 1) * WTSZ;
#pragma unroll
    for (int it = 0; it < 4; ++it) {
        const int j = it * 256 + threadIdx.x;   // 0..1023 chunk index
        const int ks = j >> 6, sub = j & 63;
        const int kgrp = sub >> 4, row = sub & 15;
        const float* src = W + (size_t)(ot * 16 + row) * CCH + ks * 32 + kgrp * 8;
        s16x8 h, l;
        load_split_frag(src, h, l);
        *(s16x8*)&hi[((size_t)(ot * 16 + ks) * 64 + sub) * 8] = h;
        *(s16x8*)&lo[((size_t)(ot * 16 + ks) * 64 + sub) * 8] = l;
    }
    if (ot == 0) {
        const float* g  = (mat == 0) ? qg  : ((mat == 1) ? kg  : pg);
        const float* be = (mat == 0) ? qbe : ((mat == 1) ? kbe : pbe);
        const float* mn = (mat == 0) ? qm  : ((mat == 1) ? km  : pm);
        const float* va = (mat == 0) ? qva : ((mat == 1) ? kva : pva);
        for (int o = threadIdx.x; o < CCH; o += 256) {
            const double inv = (double)g[o] / sqrt((double)va[o] + 1e-5);
            double add = (double)be[o] - (double)mn[o] * inv;
            if (mat == 2) add = add + (double)pb[o] * inv;
            bnc[(size_t)(mat * CCH + o) * 2]     = inv;
            bnc[(size_t)(mat * CCH + o) * 2 + 1] = add;
        }
    }
}

// ---------------------------------------------------------------------------
// q/k conv1x1 via bf16-split MFMA (3 cross terms). Block = 64o x 64hw,
// 4 waves (2 o-rows x 2 hw-halves), wave = 32o x 32hw (2 ot x 2 hwt).
// X staged as packed u32 (hi|lo) in double-buffered LDS with a 2-way-max
// bank swizzle (hw ^ (kgrp<<4)); one barrier per ks. fp64 BN/LIF epilogue,
// spikes bitpacked, near-threshold chains flagged.
// ---------------------------------------------------------------------------
template<bool PRE>
__global__ __launch_bounds__(256, 2) void k_qk(
    const float* __restrict__ x, const uint32_t* __restrict__ xsp,
    const unsigned short* __restrict__ wt, const double* __restrict__ bnc,
    uint32_t* __restrict__ qbits, uint32_t* __restrict__ kbits,
    unsigned int* __restrict__ ctr, uint32_t* __restrict__ list)
{
    __shared__ uint32_t Xs[2][8192];        // 2 x [t 4][c 32][hw-phys 64] u32
    __shared__ uint32_t QB[2][2][TT][64];   // [branch][o-word][t][hw]

    const int tid = threadIdx.x, lane = tid & 63, wid = tid >> 6;
    const int b   = blockIdx.z;
    const int o0  = blockIdx.y * 64, hw0 = blockIdx.x * 64;
    const int worow = (wid >> 1) * 32, whw = (wid & 1) * 32;

    int rowD[4], colD[4], aRow, aKb, bCol, bKb;
    probe_bf16(lane, rowD, colD, aRow, aKb, bCol, bKb);

    const int laneoff = ((aKb >> 3) * 16 + aRow) * 8;   // A-frag offset in tile
    const int kgrp = bKb >> 3;
    const int roff0 = (whw + 0  + bCol) ^ (kgrp << 4);  // swizzled hw, hwt=0
    const int roff1 = (whw + 16 + bCol) ^ (kgrp << 4);  // swizzled hw, hwt=1
    const int otg0 = blockIdx.y * 4 + (wid >> 1) * 2;   // first 16-o tile idx

    // staging tables (8 x 16B chunks per thread)
    int sDst[8];
    uint32_t sOff[8];
#pragma unroll
    for (int it = 0; it < 8; ++it) {
        const int j = it * 256 + tid;       // 0..2047
        const int t = j >> 9, c = (j >> 4) & 31, hw4 = j & 15;
        sDst[it] = (t * 32 + c) * 64 + ((hw4 * 4) ^ (((c >> 3) & 3) << 4));
        sOff[it] = (uint32_t)(((t * BB + b) * CCH + c) * HWD + hw0 + hw4 * 4);
    }

    f32x4 aq[TT][2][2], ak[TT][2][2];
#pragma unroll
    for (int t = 0; t < TT; ++t)
#pragma unroll
        for (int ot = 0; ot < 2; ++ot)
#pragma unroll
            for (int ht = 0; ht < 2; ++ht) {
                aq[t][ot][ht] = (f32x4){0.f, 0.f, 0.f, 0.f};
                ak[t][ot][ht] = (f32x4){0.f, 0.f, 0.f, 0.f};
            }

    u32x4 st[8];
    auto loadch = [&](int ks) {
#pragma unroll
        for (int it = 0; it < 8; ++it) {
            const size_t off = (size_t)sOff[it] + (size_t)ks * 32 * HWD;
            if constexpr (PRE) {
                st[it] = *(const u32x4*)&xsp[off];
            } else {
                const float4 v = *(const float4*)&x[off];
                u32x4 p;
                p[0] = packsplit(v.x); p[1] = packsplit(v.y);
                p[2] = packsplit(v.z); p[3] = packsplit(v.w);
                st[it] = p;
            }
        }
    };

    loadch(0);
#pragma unroll
    for (int it = 0; it < 8; ++it) *(u32x4*)&Xs[0][sDst[it]] = st[it];
    __syncthreads();

    int cur = 0;
#pragma unroll 1
    for (int ks = 0; ks < 16; ++ks) {
        if (ks < 15) loadch(ks + 1);

        s16x8 Aqh[2], Aql[2], Akh[2], Akl[2];
#pragma unroll
        for (int ot = 0; ot < 2; ++ot) {
            const size_t tb = ((size_t)(otg0 + ot) * 16 + ks) * 512 + laneoff;
            Aqh[ot] = *(const s16x8*)&wt[0 * WTSZ + tb];
            Aql[ot] = *(const s16x8*)&wt[1 * WTSZ + tb];
            Akh[ot] = *(const s16x8*)&wt[2 * WTSZ + tb];
            Akl[ot] = *(const s16x8*)&wt[3 * WTSZ + tb];
        }

        const uint32_t* Bb = Xs[cur];
#pragma unroll
        for (int t = 0; t < TT; ++t) {
            const uint32_t* Bp = Bb + t * 2048 + kgrp * 512;
            uint32_t w[8];
#pragma unroll
            for (int e = 0; e < 8; ++e) w[e] = Bp[e * 64 + roff0];
            u32x4 bh, bl;
            bh[0] = hi_pair(w[0], w[1]); bl[0] = lo_pair(w[0], w[1]);
            bh[1] = hi_pair(w[2], w[3]); bl[1] = lo_pair(w[2], w[3]);
            bh[2] = hi_pair(w[4], w[5]); bl[2] = lo_pair(w[4], w[5]);
            bh[3] = hi_pair(w[6], w[7]); bl[3] = lo_pair(w[6], w[7]);
            const s16x8 Bh0 = __builtin_bit_cast(s16x8, bh);
            const s16x8 Bl0 = __builtin_bit_cast(s16x8, bl);
#pragma unroll
            for (int e = 0; e < 8; ++e) w[e] = Bp[e * 64 + roff1];
            bh[0] = hi_pair(w[0], w[1]); bl[0] = lo_pair(w[0], w[1]);
            bh[1] = hi_pair(w[2], w[3]); bl[1] = lo_pair(w[2], w[3]);
            bh[2] = hi_pair(w[4], w[5]); bl[2] = lo_pair(w[4], w[5]);
            bh[3] = hi_pair(w[6], w[7]); bl[3] = lo_pair(w[6], w[7]);
            const s16x8 Bh1 = __builtin_bit_cast(s16x8, bh);
            const s16x8 Bl1 = __builtin_bit_cast(s16x8, bl);
#pragma unroll
            for (int ot = 0; ot < 2; ++ot) {
                aq[t][ot][0] = MFMA(Aqh[ot], Bh0, aq[t][ot][0]);
                aq[t][ot][0] = MFMA(Aqh[ot], Bl0, aq[t][ot][0]);
                aq[t][ot][0] = MFMA(Aql[ot], Bh0, aq[t][ot][0]);
                ak[t][ot][0] = MFMA(Akh[ot], Bh0, ak[t][ot][0]);
                ak[t][ot][0] = MFMA(Akh[ot], Bl0, ak[t][ot][0]);
                ak[t][ot][0] = MFMA(Akl[ot], Bh0, ak[t][ot][0]);
                aq[t][ot][1] = MFMA(Aqh[ot], Bh1, aq[t][ot][1]);
                aq[t][ot][1] = MFMA(Aqh[ot], Bl1, aq[t][ot][1]);
                aq[t][ot][1] = MFMA(Aql[ot], Bh1, aq[t][ot][1]);
                ak[t][ot][1] = MFMA(Akh[ot], Bh1, ak[t][ot][1]);
                ak[t][ot][1] = MFMA(Akh[ot], Bl1, ak[t][ot][1]);
                ak[t][ot][1] = MFMA(Akl[ot], Bh1, ak[t][ot][1]);
            }
        }

        if (ks < 15) {
#pragma unroll
            for (int it = 0; it < 8; ++it) *(u32x4*)&Xs[cur ^ 1][sDst[it]] = st[it];
        }
        __syncthreads();
        cur ^= 1;
    }

    // ---- epilogue: fp64 BN + LIF, flags, bitpack ----
#pragma unroll
    for (int u = 0; u < 8; ++u) ((uint32_t*)QB)[tid + u * 256] = 0u;
    __syncthreads();

    auto chains = [&](f32x4 (&acc)[TT][2][2], int br) {
#pragma unroll
        for (int ot = 0; ot < 2; ++ot)
#pragma unroll
            for (int ht = 0; ht < 2; ++ht)
#pragma unroll
                for (int r = 0; r < 4; ++r) {
                    const int orow = worow + ot * 16 + rowD[r];    // 0..63
                    const int o = o0 + orow;
                    const double inv = bnc[(size_t)(br * CCH + o) * 2];
                    const double add = bnc[(size_t)(br * CCH + o) * 2 + 1];
                    const uint32_t bit = 1u << (orow & 31);
                    const int ow = orow >> 5;
                    const int hwq = whw + ht * 16 + colD[r];       // 0..63
                    double v = 0.0; bool fl = false;
#pragma unroll
                    for (int t = 0; t < TT; ++t) {
                        const double y = (double)acc[t][ot][ht][r] * inv + add;
                        v = v + (y - v) * 0.5;
                        if (fabs(v - 1.0) < MQK) fl = true;
                        if (v >= 1.0) { atomicOr(&QB[br][ow][t][hwq], bit); v = 0.0; }
                    }
                    if (fl) {
                        const unsigned int idx = atomicAdd(ctr, 1u);
                        if (idx < CAPQ)
                            list[idx] = (uint32_t)((br << 23) | (o << 14) | (b << 10) | (hw0 + hwq));
                    }
                }
    };
    chains(aq, 0);
    chains(ak, 1);
    __syncthreads();

#pragma unroll
    for (int u = 0; u < 4; ++u) {
        const int idx = tid + u * 256;   // 0..1023
        const int br = idx >> 9, ow = (idx >> 8) & 1, t = (idx >> 6) & 3, hwq = idx & 63;
        uint32_t* dst = br ? kbits : qbits;
        dst[((size_t)(t * BB + b) * NW + (o0 >> 5) + ow) * HWD + hw0 + hwq] = QB[br][ow][t][hwq];
    }
}

// ---------------------------------------------------------------------------
// Exact fp64 recompute of flagged q/k chains; patch spike bits.
// ---------------------------------------------------------------------------
__global__ __launch_bounds__(256) void k_fix_qk(
    const float* __restrict__ x,
    const float* __restrict__ qw, const float* __restrict__ qg, const float* __restrict__ qbe,
    const float* __restrict__ qm, const float* __restrict__ qva,
    const float* __restrict__ kw, const float* __restrict__ kg, const float* __restrict__ kbe,
    const float* __restrict__ km, const float* __restrict__ kva,
    const unsigned int* __restrict__ ctr, const uint32_t* __restrict__ list,
    uint32_t* __restrict__ qbits, uint32_t* __restrict__ kbits)
{
    const int lane = threadIdx.x & 63;
    const int wg = (blockIdx.x * blockDim.x + threadIdx.x) >> 6;
    const int nw = (gridDim.x * blockDim.x) >> 6;
    unsigned int n = *ctr; if (n > CAPQ) n = CAPQ;

    for (unsigned int i = wg; i < n; i += nw) {
        const uint32_t e = list[i];
        const int br = (e >> 23) & 1, o = (e >> 14) & 511, b = (e >> 10) & 15, hw = e & 1023;
        const float* w = (br ? kw : qw) + (size_t)o * CCH;
        double dots[TT];
#pragma unroll
        for (int t = 0; t < TT; ++t) {
            double s = 0.0;
            for (int c = lane; c < CCH; c += 64)
                s += (double)w[c] * (double)x[((size_t)(t * BB + b) * CCH + c) * HWD + hw];
#pragma unroll
            for (int off = 32; off; off >>= 1) s += __shfl_xor(s, off);
            dots[t] = s;
        }
        if (lane == 0) {
            const float* g  = br ? kg  : qg;
            const float* be = br ? kbe : qbe;
            const float* mn = br ? km  : qm;
            const float* va = br ? kva : qva;
            const double inv = (double)g[o] / sqrt((double)va[o] + 1e-5);
            const double add = (double)be[o] - (double)mn[o] * inv;
            uint32_t* bits = br ? kbits : qbits;
            double v = 0.0;
#pragma unroll
            for (int t = 0; t < TT; ++t) {
                const double y = dots[t] * inv + add;
                v = v + (y - v) * 0.5;
                const size_t wa = ((size_t)(t * BB + b) * NW + (o >> 5)) * HWD + hw;
                const uint32_t bit = 1u << (o & 31);
                if (v >= 1.0) { atomicOr(&bits[wa], bit); v = 0.0; }
                else          { atomicAnd(&bits[wa], ~bit); }
            }
        }
    }
}

// ---------------------------------------------------------------------------
// Head-sum of q spikes (popcount) + LIF at 0.5 (exact dyadic).
// ---------------------------------------------------------------------------
__global__ __launch_bounds__(256) void k_attn(
    const uint32_t* __restrict__ qbits, uint8_t* __restrict__ attn)
{
    const int idx = blockIdx.x * 256 + threadIdx.x;
    const int hw = idx & (HWD - 1);
    const int h  = (idx >> 10) & (NHH - 1);
    const int b  = idx >> 13;
    double v = 0.0;
#pragma unroll
    for (int t = 0; t < TT; ++t) {
        const uint32_t w0 = qbits[((size_t)(t * BB + b) * NW + h * 2    ) * HWD + hw];
        const uint32_t w1 = qbits[((size_t)(t * BB + b) * NW + h * 2 + 1) * HWD + hw];
        const double q = (double)(__popc(w0) + __popc(w1));
        v = v + (q - v) * 0.5;
        const uint8_t s = (v >= 0.5) ? (uint8_t)1 : (uint8_t)0;
        attn[((size_t)(t * BB + b) * NHH + h) * HWD + hw] = s;
        if (s) v = 0.0;
    }
}

// ---------------------------------------------------------------------------
// proj conv via bf16 MFMA over binary y = attn & k (exact in bf16; A from
// pre-split tiles -> 2 terms) + fp64 bias/BN/LIF + flags.
// Block = 128o x 32hw, 4 waves (2o x 2hw), wave = 64o x 16hw.
// ---------------------------------------------------------------------------
__global__ __launch_bounds__(256) void k_proj(
    const unsigned short* __restrict__ wt, const double* __restrict__ bnc,
    const uint32_t* __restrict__ kbits, const uint8_t* __restrict__ attn,
    float* __restrict__ out,
    unsigned int* __restrict__ ctr2, uint32_t* __restrict__ list2)
{
    const int tid = threadIdx.x, lane = tid & 63, wid = tid >> 6;
    const int b   = blockIdx.z;
    const int o0  = blockIdx.y * 128, hw0 = blockIdx.x * 32;
    const int worow = (wid >> 1) * 64, whw = (wid & 1) * 16;

    int rowD[4], colD[4], aRow, aKb, bCol, bKb;
    probe_bf16(lane, rowD, colD, aRow, aKb, bCol, bKb);
    const int laneoff = ((aKb >> 3) * 16 + aRow) * 8;
    const int hwB = hw0 + whw + bCol;
    const int otg0 = blockIdx.y * 8 + (wid >> 1) * 4;

    f32x4 acc[TT][4];
#pragma unroll
    for (int t = 0; t < TT; ++t)
#pragma unroll
        for (int ot = 0; ot < 4; ++ot) acc[t][ot] = (f32x4){0.f, 0.f, 0.f, 0.f};

#pragma unroll 1
    for (int ks = 0; ks < 16; ++ks) {
        s16x8 Ah[4], Al[4];
#pragma unroll
        for (int ot = 0; ot < 4; ++ot) {
            const size_t tb = ((size_t)(otg0 + ot) * 16 + ks) * 512 + laneoff;
            Ah[ot] = *(const s16x8*)&wt[4 * WTSZ + tb];
            Al[ot] = *(const s16x8*)&wt[5 * WTSZ + tb];
        }
#pragma unroll
        for (int t = 0; t < TT; ++t) {
            const size_t tb = (size_t)(t * BB + b);
            const uint32_t kv = kbits[(tb * NW + ks) * HWD + hwB];
            const uint32_t av = attn[(tb * NHH + (ks >> 1)) * HWD + hwB];
            const uint32_t mask = av ? kv : 0u;
            const uint32_t byt = (mask >> bKb) & 0xFFu;
            u32x4 bw;
#pragma unroll
            for (int j = 0; j < 4; ++j)
                bw[j] = (((byt >> (2 * j)) & 1u) ? 0x3F80u : 0u)
                      | (((byt >> (2 * j + 1)) & 1u) ? 0x3F800000u : 0u);
            const s16x8 By = __builtin_bit_cast(s16x8, bw);
#pragma unroll
            for (int ot = 0; ot < 4; ++ot) {
                acc[t][ot] = MFMA(Ah[ot], By, acc[t][ot]);
                acc[t][ot] = MFMA(Al[ot], By, acc[t][ot]);
            }
        }
    }

    // ---- epilogue: fp64 BN (bias folded) + LIF + store + flags ----
#pragma unroll
    for (int ot = 0; ot < 4; ++ot)
#pragma unroll
        for (int r = 0; r < 4; ++r) {
            const int o = o0 + worow + ot * 16 + rowD[r];
            const int hwD = hw0 + whw + colD[r];
            const double inv = bnc[(size_t)(2 * CCH + o) * 2];
            const double add = bnc[(size_t)(2 * CCH + o) * 2 + 1];
            double v = 0.0; bool fl = false;
#pragma unroll
            for (int t = 0; t < TT; ++t) {
                const double y = (double)acc[t][ot][r] * inv + add;
                v = v + (y - v) * 0.5;
                if (fabs(v - 1.0) < MPROJ) fl = true;
                float s;
                if (v >= 1.0) { s = 1.0f; v = 0.0; } else { s = 0.0f; }
                out[((size_t)(t * BB + b) * CCH + o) * HWD + hwD] = s;
            }
            if (fl) {
                const unsigned int idx = atomicAdd(ctr2, 1u);
                if (idx < CAPP) list2[idx] = (uint32_t)((o << 14) | (b << 10) | hwD);
            }
        }
}

// ---------------------------------------------------------------------------
// Exact fp64 recompute of flagged proj chains; patch d_out.
// ---------------------------------------------------------------------------
__global__ __launch_bounds__(256) void k_fix_proj(
    const float* __restrict__ pw, const float* __restrict__ pb,
    const float* __restrict__ pg, const float* __restrict__ pbe,
    const float* __restrict__ pm, const float* __restrict__ pva,
    const uint32_t* __restrict__ kbits, const uint8_t* __restrict__ attn,
    const unsigned int* __restrict__ ctr2, const uint32_t* __restrict__ list2,
    float* __restrict__ out)
{
    const int lane = threadIdx.x & 63;
    const int wg = (blockIdx.x * blockDim.x + threadIdx.x) >> 6;
    const int nw = (gridDim.x * blockDim.x) >> 6;
    unsigned int n = *ctr2; if (n > CAPP) n = CAPP;

    for (unsigned int i = wg; i < n; i += nw) {
        const uint32_t e = list2[i];
        const int o = (e >> 14) & 511, b = (e >> 10) & 15, hw = e & 1023;
        const float* w = pw + (size_t)o * CCH;
        double dots[TT];
#pragma unroll
        for (int t = 0; t < TT; ++t) {
            double s = 0.0;
            for (int c = lane; c < CCH; c += 64) {
                const uint32_t kv = kbits[((size_t)(t * BB + b) * NW + (c >> 5)) * HWD + hw];
                const uint32_t av = attn[((size_t)(t * BB + b) * NHH + (c >> 6)) * HWD + hw];
                if (av && ((kv >> (c & 31)) & 1u)) s += (double)w[c];
            }
#pragma unroll
            for (int off = 32; off; off >>= 1) s += __shfl_xor(s, off);
            dots[t] = s;
        }
        if (lane == 0) {
            const double inv = (double)pg[o] / sqrt((double)pva[o] + 1e-5);
            const double add = (double)pbe[o] - (double)pm[o] * inv;
            const double bias = (double)pb[o];
            double v = 0.0;
#pragma unroll
            for (int t = 0; t < TT; ++t) {
                const double y = (dots[t] + bias) * inv + add;
                v = v + (y - v) * 0.5;
                float s;
                if (v >= 1.0) { s = 1.0f; v = 0.0; } else { s = 0.0f; }
                out[((size_t)(t * BB + b) * CCH + o) * HWD + hw] = s;
            }
        }
    }
}

extern "C" void kernel_launch(void* const* d_in, const int* in_sizes, int n_in,
                              void* d_out, int out_size, void* d_ws, size_t ws_size,
                              hipStream_t stream)
{
    (void)in_sizes; (void)n_in; (void)out_size;

    const float* x   = (const float*)d_in[0];
    const float* qw  = (const float*)d_in[1];
    const float* qg  = (const float*)d_in[2];
    const float* qbe = (const float*)d_in[3];
    const float* qm  = (const float*)d_in[4];
    const float* qv  = (const float*)d_in[5];
    const float* kw  = (const float*)d_in[6];
    const float* kg  = (const float*)d_in[7];
    const float* kbe = (const float*)d_in[8];
    const float* km  = (const float*)d_in[9];
    const float* kv  = (const float*)d_in[10];
    const float* pw  = (const float*)d_in[11];
    const float* pb  = (const float*)d_in[12];
    const float* pg  = (const float*)d_in[13];
    const float* pbe = (const float*)d_in[14];
    const float* pm  = (const float*)d_in[15];
    const float* pv  = (const float*)d_in[16];

    uint8_t* base = (uint8_t*)d_ws;
    uint32_t* qbits = (uint32_t*)base;                              // 4 MiB
    uint32_t* kbits = (uint32_t*)(base + 4194304);                  // 4 MiB
    uint8_t*  attn  = base + 8388608;                               // 512 KiB
    unsigned int* ctr = (unsigned int*)(base + 8912896);            // 256 B
    uint32_t* qklist  = (uint32_t*)(base + 8913152);                // 192 KiB
    uint32_t* prlist  = (uint32_t*)(base + 9109760);                // 64 KiB
    unsigned short* wtiles = (unsigned short*)(base + 9175296);     // 3 MiB
    double* bnc = (double*)(base + 12321024);                       // 24 KiB
    uint32_t* xsp = (uint32_t*)(base + XSOFF);                      // 128 MiB
    float* out = (float*)d_out;

    const bool pre = ws_size >= WSNEED;

    k_zero<<<1, 64, 0, stream>>>(ctr);
    k_prep<<<96, 256, 0, stream>>>(qw, kw, pw, qg, qbe, qm, qv,
                                   kg, kbe, km, kv, pg, pbe, pm, pv, pb,
                                   wtiles, bnc);
    if (pre) {
        k_xsplit<<<2048, 256, 0, stream>>>(x, xsp);
        k_qk<true><<<dim3(HWD / 64, CCH / 64, BB), 256, 0, stream>>>(
            x, xsp, wtiles, bnc, qbits, kbits, ctr, qklist);
    } else {
        k_qk<false><<<dim3(HWD / 64, CCH / 64, BB), 256, 0, stream>>>(
            x, xsp, wtiles, bnc, qbits, kbits, ctr, qklist);
    }
    k_fix_qk<<<256, 256, 0, stream>>>(x, qw, qg, qbe, qm, qv,
                                      kw, kg, kbe, km, kv, ctr, qklist, qbits, kbits);
    k_attn<<<(BB * NHH * HWD) / 256, 256, 0, stream>>>(qbits, attn);
    k_proj<<<dim3(HWD / 32, CCH / 128, BB), 256, 0, stream>>>(
        wtiles, bnc, kbits, attn, out, ctr + 1, prlist);
    k_fix_proj<<<64, 256, 0, stream>>>(pw, pb, pg, pbe, pm, pv,
                                       kbits, attn, ctr + 1, prlist, out);
}